// Round 7
// baseline (1337.567 us; speedup 1.0000x reference)
//
#include <hip/hip_runtime.h>
#include <cstddef>

#define NN   20000          // real nodes
#define NG   200            // graphs / virtual nodes
#define NE   320000         // original edges
#define NAUG 20200          // NN + NG
#define NE2  360000         // NE + 2*NN  (edges before self-loops)
#define EAUG 380200         // NE2 + NAUG
#define DD   64             // NUM_EMB
#define HC   128            // HEADS * NUM_EMB

typedef float  f32x4 __attribute__((ext_vector_type(4)));
typedef short  s16x8 __attribute__((ext_vector_type(8)));

static __device__ __forceinline__ unsigned short bf16r(float f){
  unsigned u = __float_as_uint(f);
  u += 0x7FFFu + ((u >> 16) & 1u);
  return (unsigned short)(u >> 16);
}
static __device__ __forceinline__ float4 b2f4(ushort4 u){
  return make_float4(__uint_as_float((unsigned)u.x << 16),
                     __uint_as_float((unsigned)u.y << 16),
                     __uint_as_float((unsigned)u.z << 16),
                     __uint_as_float((unsigned)u.w << 16));
}
static __device__ __forceinline__ ushort4 f2b4(float4 v){
  ushort4 s; s.x=bf16r(v.x); s.y=bf16r(v.y); s.z=bf16r(v.z); s.w=bf16r(v.w); return s;
}
static __device__ __forceinline__ float d4(float4 a, float4 b){
  return a.x*b.x + a.y*b.y + a.z*b.z + a.w*b.w;
}
static __device__ __forceinline__ float4 f4ab(float4 a, float s, float4 b, float t){
  return make_float4(a.x*s + b.x*t, a.y*s + b.y*t, a.z*s + b.z*t, a.w*s + b.w*t);
}
static __device__ __forceinline__ float4 f4s(float4 a, float s){
  return make_float4(a.x*s, a.y*s, a.z*s, a.w*s);
}

// =====================================================================
// Weight pre-conversion: fp32 -> bf16, transposed to Bt[n][k], stride KP=K+8
// {srcIdx, mode, Ksrc, N, KP, stride, soff}; mode0 transpose, mode1 direct
// =====================================================================
#define WTAB_INIT { \
  {0,0,128,128,136,128,0},{0,0,128,128,136,128,16384},{0,0,128,128,136,128,32768}, \
  {1,0,128,128,136,128,0},{1,0,128,128,136,128,16384},{1,0,128,128,136,128,32768}, \
  {2,0,128,128,136,128,0},{2,0,128,128,136,128,16384},{2,0,128,128,136,128,32768}, \
  {3,0,128,128,136,128,0},{3,0,128,128,136,128,16384},{3,0,128,128,136,128,32768}, \
  {4,0,64,64,72,64,0},{4,0,64,64,72,64,4096},{4,0,64,64,72,64,8192}, \
  {5,0,128,64,136,64,0},{5,0,128,64,136,64,8192},{5,0,128,64,136,64,16384}, \
  {6,0,64,256,72,256,0},{6,0,64,256,72,256,16384},{6,0,64,256,72,256,32768}, \
  {7,0,256,64,264,64,0},{7,0,256,64,264,64,16384},{7,0,256,64,264,64,32768}, \
  {8,1,64,64,72,128,0},{8,1,64,64,72,128,64},{8,1,64,64,72,128,8192},{8,1,64,64,72,128,8256},{8,1,64,64,72,128,16384},{8,1,64,64,72,128,16448}, \
  {8,0,64,64,72,128,0},{8,0,64,64,72,128,64},{8,0,64,64,72,128,8192},{8,0,64,64,72,128,8256},{8,0,64,64,72,128,16384},{8,0,64,64,72,128,16448}, \
  {9,0,32,64,40,64,0},{10,0,64,64,72,64,0},{11,0,64,64,72,64,0}, \
  {12,0,16,64,40,64,0},{13,0,64,64,72,64,0},{14,0,64,64,72,64,0}, \
  {15,0,32,64,40,64,0},{16,0,64,64,72,64,0},{17,0,64,64,72,64,0} }

static const int WTAB_H[45][7] = WTAB_INIT;
__device__ static const int WTAB_D[45][7] = WTAB_INIT;

struct WPtrs { const float* p[18]; };

__global__ void wconv_all_k(WPtrs wp, unsigned short* __restrict__ outbase){
  int b = blockIdx.x;
  int acc = 0; unsigned ooff = 0;
  #pragma unroll 1
  for (int j = 0; j < 45; j++){
    int e  = WTAB_D[j][3] * WTAB_D[j][4];
    int nb = (e + 255) >> 8;
    if (b < acc + nb){
      int idx = (b - acc)*256 + threadIdx.x;
      if (idx < e){
        int KP = WTAB_D[j][4];
        int n = idx / KP, k = idx % KP;
        float v = 0.f;
        if (k < WTAB_D[j][2]){
          const float* s = wp.p[WTAB_D[j][0]];
          int st = WTAB_D[j][5], so = WTAB_D[j][6];
          v = (WTAB_D[j][1] == 0) ? s[(size_t)so + (size_t)k*st + n]
                                  : s[(size_t)so + (size_t)n*st + k];
        }
        outbase[ooff + idx] = bf16r(v);
      }
      return;
    }
    acc += nb; ooff += (unsigned)e;
  }
}

// =====================================================================
// Generic MFMA GEMM (template N): out = act(A(+A2) @ W + bias) + res(+res2)
// =====================================================================
template<int NT>
__launch_bounds__(256)
__global__ void gemm_mfma_k(const float* __restrict__ A, const float* __restrict__ A2,
                            int M, int K, int lda,
                            const unsigned short* __restrict__ WtG,
                            const float* __restrict__ bias, int act,
                            const float* __restrict__ res, const float* __restrict__ res2,
                            int rstride, float* __restrict__ out, int ostride){
  extern __shared__ unsigned short smem[];
  const int KC  = (K > 128) ? 128 : K;
  const int KPc = KC + 8;
  const int KP  = K + 8;
  unsigned short* Wts  = smem;            // NT * KPc
  unsigned short* Asub = smem + NT*KPc;   // 64 * KPc
  const int tid = threadIdx.x;
  const int wid = tid >> 6, lane = tid & 63;
  const int lrow = lane & 15, quad = lane >> 4;
  const int m0 = blockIdx.x * 64;
  f32x4 acc[NT/16];
  #pragma unroll
  for (int t = 0; t < NT/16; t++) acc[t] = (f32x4){0.f,0.f,0.f,0.f};

  for (int k0 = 0; k0 < K; k0 += KC){
    const int wv = NT*KPc/8, wrow = KPc/8;
    for (int i = tid; i < wv; i += 256){
      int n = i / wrow, c8 = i % wrow;
      *(uint4*)&Wts[n*KPc + c8*8] = *(const uint4*)&WtG[(size_t)n*KP + k0 + c8*8];
    }
    const int av = 64*KC/4, arow = KC/4;
    for (int i = tid; i < av; i += 256){
      int r = i / arow, c4i = i % arow;
      int m = m0 + r, k = k0 + c4i*4;
      float4 v = make_float4(0.f,0.f,0.f,0.f);
      if (m < M){
        v = *(const float4*)(A + (size_t)m*lda + k);
        if (A2){ float4 w = *(const float4*)(A2 + (size_t)m*lda + k);
                 v.x += w.x; v.y += w.y; v.z += w.z; v.w += w.w; }
      }
      *(ushort4*)&Asub[r*KPc + c4i*4] = f2b4(v);
    }
    __syncthreads();
    const int ksteps = KC >> 5;
    for (int ks = 0; ks < ksteps; ks++){
      s16x8 a = *(const s16x8*)&Asub[(wid*16 + lrow)*KPc + ks*32 + quad*8];
      #pragma unroll
      for (int nt = 0; nt < NT/16; nt++){
        s16x8 b = *(const s16x8*)&Wts[(nt*16 + lrow)*KPc + ks*32 + quad*8];
        acc[nt] = __builtin_amdgcn_mfma_f32_16x16x32_bf16(a, b, acc[nt], 0, 0, 0);
      }
    }
    __syncthreads();
  }

  const int mb = m0 + wid*16 + quad*4;
  #pragma unroll
  for (int nt = 0; nt < NT/16; nt++){
    int n = nt*16 + lrow;
    #pragma unroll
    for (int r = 0; r < 4; r++){
      int m = mb + r;
      if (m < M){
        float v = acc[nt][r];
        if (bias) v += bias[n];
        if (act)  v = v > 0.f ? v : 0.01f*v;
        if (res)  v += res [(size_t)m*rstride + n];
        if (res2) v += res2[(size_t)m*rstride + n];
        out[(size_t)m*ostride + n] = v;
      }
    }
  }
}

// =====================================================================
// Batched QKVS GEMM: grid.y selects weight; out[m, y*128 + n], ostride 512
// =====================================================================
struct PW4 { const unsigned short* w[4]; const float* b[4]; };

__launch_bounds__(256)
__global__ void qkvs4_k(const float* __restrict__ A, int M, PW4 pw,
                        float* __restrict__ out){
  __shared__ __align__(16) unsigned short Wts[128*136];
  __shared__ __align__(16) unsigned short Asub[64*136];
  const unsigned short* WtG = pw.w[blockIdx.y];
  const float* bias = pw.b[blockIdx.y];
  const int tid = threadIdx.x;
  const int wid = tid >> 6, lane = tid & 63;
  const int lrow = lane & 15, quad = lane >> 4;
  const int m0 = blockIdx.x * 64;
  for (int i = tid; i < 128*17; i += 256){
    int n = i/17, c8 = i%17;
    *(uint4*)&Wts[n*136 + c8*8] = *(const uint4*)&WtG[(size_t)n*136 + c8*8];
  }
  for (int i = tid; i < 64*32; i += 256){
    int r = i >> 5, c4 = (i & 31)*4;
    int m = m0 + r;
    float4 v = make_float4(0.f,0.f,0.f,0.f);
    if (m < M) v = *(const float4*)(A + (size_t)m*128 + c4);
    *(ushort4*)&Asub[r*136 + c4] = f2b4(v);
  }
  __syncthreads();
  f32x4 acc[8];
  #pragma unroll
  for (int t=0;t<8;t++) acc[t] = (f32x4){0.f,0.f,0.f,0.f};
  #pragma unroll
  for (int ks = 0; ks < 4; ks++){
    s16x8 a = *(const s16x8*)&Asub[(wid*16 + lrow)*136 + ks*32 + quad*8];
    #pragma unroll
    for (int nt = 0; nt < 8; nt++){
      s16x8 b = *(const s16x8*)&Wts[(nt*16 + lrow)*136 + ks*32 + quad*8];
      acc[nt] = __builtin_amdgcn_mfma_f32_16x16x32_bf16(a, b, acc[nt], 0, 0, 0);
    }
  }
  const int mb = m0 + wid*16 + quad*4;
  const int yoff = blockIdx.y*128;
  #pragma unroll
  for (int nt = 0; nt < 8; nt++){
    int n = nt*16 + lrow;
    #pragma unroll
    for (int r = 0; r < 4; r++){
      int m = mb + r;
      if (m < M) out[(size_t)m*512 + yoff + n] = acc[nt][r] + bias[n];
    }
  }
}

// =====================================================================
// Batched per-head 64x64 GEMMs (qe, tout) — grid.y = head
// =====================================================================
struct PW2 { const unsigned short* w[2]; };

__launch_bounds__(256)
__global__ void qe2_k(const float* __restrict__ qkvs, int M, PW2 pw,
                      float* __restrict__ qe){
  __shared__ __align__(16) unsigned short Wts[64*72];
  __shared__ __align__(16) unsigned short Asub[64*72];
  const unsigned short* WtG = pw.w[blockIdx.y];
  const int tid = threadIdx.x;
  const int wid = tid >> 6, lane = tid & 63;
  const int lrow = lane & 15, quad = lane >> 4;
  const int m0 = blockIdx.x * 64;
  const int yoff = blockIdx.y * 64;
  for (int i = tid; i < 64*9; i += 256){
    int n = i/9, c8 = i%9;
    *(uint4*)&Wts[n*72 + c8*8] = *(const uint4*)&WtG[(size_t)n*72 + c8*8];
  }
  for (int i = tid; i < 64*16; i += 256){
    int r = i >> 4, c4 = (i & 15)*4;
    int m = m0 + r;
    float4 v = make_float4(0.f,0.f,0.f,0.f);
    if (m < M) v = *(const float4*)(qkvs + (size_t)m*512 + yoff + c4);
    *(ushort4*)&Asub[r*72 + c4] = f2b4(v);
  }
  __syncthreads();
  f32x4 acc[4];
  #pragma unroll
  for (int t=0;t<4;t++) acc[t] = (f32x4){0.f,0.f,0.f,0.f};
  #pragma unroll
  for (int ks = 0; ks < 2; ks++){
    s16x8 a = *(const s16x8*)&Asub[(wid*16 + lrow)*72 + ks*32 + quad*8];
    #pragma unroll
    for (int nt = 0; nt < 4; nt++){
      s16x8 b = *(const s16x8*)&Wts[(nt*16 + lrow)*72 + ks*32 + quad*8];
      acc[nt] = __builtin_amdgcn_mfma_f32_16x16x32_bf16(a, b, acc[nt], 0, 0, 0);
    }
  }
  const int mb = m0 + wid*16 + quad*4;
  #pragma unroll
  for (int nt = 0; nt < 4; nt++){
    int n = nt*16 + lrow;
    #pragma unroll
    for (int r = 0; r < 4; r++){
      int m = mb + r;
      if (m < M) qe[(size_t)m*HC + yoff + n] = acc[nt][r];
    }
  }
}

__launch_bounds__(256)
__global__ void tout2_k(const float* __restrict__ wv, int M, PW2 pw,
                        const float* __restrict__ t1, const float* __restrict__ qkvs,
                        float* __restrict__ tout){
  __shared__ __align__(16) unsigned short Wts[64*72];
  __shared__ __align__(16) unsigned short Asub[64*72];
  const unsigned short* WtG = pw.w[blockIdx.y];
  const int tid = threadIdx.x;
  const int wid = tid >> 6, lane = tid & 63;
  const int lrow = lane & 15, quad = lane >> 4;
  const int m0 = blockIdx.x * 64;
  const int yoff = blockIdx.y * 64;
  for (int i = tid; i < 64*9; i += 256){
    int n = i/9, c8 = i%9;
    *(uint4*)&Wts[n*72 + c8*8] = *(const uint4*)&WtG[(size_t)n*72 + c8*8];
  }
  for (int i = tid; i < 64*16; i += 256){
    int r = i >> 4, c4 = (i & 15)*4;
    int m = m0 + r;
    float4 v = make_float4(0.f,0.f,0.f,0.f);
    if (m < M) v = *(const float4*)(wv + (size_t)m*HC + yoff + c4);
    *(ushort4*)&Asub[r*72 + c4] = f2b4(v);
  }
  __syncthreads();
  f32x4 acc[4];
  #pragma unroll
  for (int t=0;t<4;t++) acc[t] = (f32x4){0.f,0.f,0.f,0.f};
  #pragma unroll
  for (int ks = 0; ks < 2; ks++){
    s16x8 a = *(const s16x8*)&Asub[(wid*16 + lrow)*72 + ks*32 + quad*8];
    #pragma unroll
    for (int nt = 0; nt < 4; nt++){
      s16x8 b = *(const s16x8*)&Wts[(nt*16 + lrow)*72 + ks*32 + quad*8];
      acc[nt] = __builtin_amdgcn_mfma_f32_16x16x32_bf16(a, b, acc[nt], 0, 0, 0);
    }
  }
  const int mb = m0 + wid*16 + quad*4;
  #pragma unroll
  for (int nt = 0; nt < 4; nt++){
    int n = nt*16 + lrow;
    #pragma unroll
    for (int r = 0; r < 4; r++){
      int m = mb + r;
      if (m < M)
        tout[(size_t)m*HC + yoff + n] = acc[nt][r]
          + t1[(size_t)m*HC + yoff + n] + qkvs[(size_t)m*512 + 384 + yoff + n];
    }
  }
}

// =====================================================================
// Fused 3-layer MLP via MFMA; fp32 out OR bf16 out with row permutation
// =====================================================================
__launch_bounds__(256)
__global__ void mlp3_mfma_k(const float* __restrict__ X, int M, int Din,
                            const unsigned short* __restrict__ w1t,
                            const unsigned short* __restrict__ w2t,
                            const unsigned short* __restrict__ w3t,
                            const float* __restrict__ b1, const float* __restrict__ b2,
                            const float* __restrict__ b3,
                            const int* __restrict__ perm, float* __restrict__ out,
                            unsigned short* __restrict__ outb){
  __shared__ __align__(16) unsigned short W1s[64*40], W2s[64*72], W3s[64*72];
  __shared__ __align__(16) unsigned short xs[64*40], hs[64*72];
  __shared__ float bsh[192];
  const int tid = threadIdx.x;
  for (int i = tid; i < 320; i += 256)  *(uint4*)&W1s[i*8] = *(const uint4*)&w1t[i*8];
  for (int i = tid; i < 576; i += 256){ *(uint4*)&W2s[i*8] = *(const uint4*)&w2t[i*8];
                                        *(uint4*)&W3s[i*8] = *(const uint4*)&w3t[i*8]; }
  if (tid < 64){ bsh[tid] = b1[tid]; bsh[64+tid] = b2[tid]; bsh[128+tid] = b3[tid]; }
  const int m0 = blockIdx.x * 64;
  for (int i = tid; i < 512; i += 256){
    int r = i >> 3, c4 = (i & 7) * 4;
    int m = m0 + r;
    float4 v = make_float4(0.f,0.f,0.f,0.f);
    if (m < M && c4 < Din) v = *(const float4*)(X + (size_t)m*Din + c4);
    *(ushort4*)&xs[r*40 + c4] = f2b4(v);
  }
  __syncthreads();
  const int wid = tid >> 6, lane = tid & 63;
  const int lrow = lane & 15, quad = lane >> 4;
  f32x4 acc[4];

  #pragma unroll
  for (int t = 0; t < 4; t++) acc[t] = (f32x4){0.f,0.f,0.f,0.f};
  {
    s16x8 a = *(const s16x8*)&xs[(wid*16 + lrow)*40 + quad*8];
    #pragma unroll
    for (int nt = 0; nt < 4; nt++){
      s16x8 b = *(const s16x8*)&W1s[(nt*16 + lrow)*40 + quad*8];
      acc[nt] = __builtin_amdgcn_mfma_f32_16x16x32_bf16(a, b, acc[nt], 0, 0, 0);
    }
  }
  #pragma unroll
  for (int nt = 0; nt < 4; nt++){
    int n = nt*16 + lrow;
    #pragma unroll
    for (int r = 0; r < 4; r++){
      float v = acc[nt][r] + bsh[n];
      v = v > 0.f ? v : 0.01f*v;
      hs[(wid*16 + quad*4 + r)*72 + n] = bf16r(v);
    }
  }
  __syncthreads();

  #pragma unroll
  for (int t = 0; t < 4; t++) acc[t] = (f32x4){0.f,0.f,0.f,0.f};
  #pragma unroll
  for (int ks = 0; ks < 2; ks++){
    s16x8 a = *(const s16x8*)&hs[(wid*16 + lrow)*72 + ks*32 + quad*8];
    #pragma unroll
    for (int nt = 0; nt < 4; nt++){
      s16x8 b = *(const s16x8*)&W2s[(nt*16 + lrow)*72 + ks*32 + quad*8];
      acc[nt] = __builtin_amdgcn_mfma_f32_16x16x32_bf16(a, b, acc[nt], 0, 0, 0);
    }
  }
  __syncthreads();
  #pragma unroll
  for (int nt = 0; nt < 4; nt++){
    int n = nt*16 + lrow;
    #pragma unroll
    for (int r = 0; r < 4; r++){
      float v = acc[nt][r] + bsh[64 + n];
      v = v > 0.f ? v : 0.01f*v;
      hs[(wid*16 + quad*4 + r)*72 + n] = bf16r(v);
    }
  }
  __syncthreads();

  #pragma unroll
  for (int t = 0; t < 4; t++) acc[t] = (f32x4){0.f,0.f,0.f,0.f};
  #pragma unroll
  for (int ks = 0; ks < 2; ks++){
    s16x8 a = *(const s16x8*)&hs[(wid*16 + lrow)*72 + ks*32 + quad*8];
    #pragma unroll
    for (int nt = 0; nt < 4; nt++){
      s16x8 b = *(const s16x8*)&W3s[(nt*16 + lrow)*72 + ks*32 + quad*8];
      acc[nt] = __builtin_amdgcn_mfma_f32_16x16x32_bf16(a, b, acc[nt], 0, 0, 0);
    }
  }
  #pragma unroll
  for (int nt = 0; nt < 4; nt++){
    int n = nt*16 + lrow;
    #pragma unroll
    for (int r = 0; r < 4; r++){
      int m = m0 + wid*16 + quad*4 + r;
      if (m < M){
        int orow = perm ? perm[m] : m;
        float v = acc[nt][r] + bsh[128 + n];
        if (outb) outb[(size_t)orow*64 + n] = bf16r(v);
        else      out [(size_t)orow*64 + n] = v;
      }
    }
  }
}

// ---------- build augmented edge list ----------
__global__ void build_edges_k(const int* __restrict__ ei, const int* __restrict__ batch,
                              int* __restrict__ srcA, int* __restrict__ dstA){
  int idx = blockIdx.x*256 + threadIdx.x;
  if (idx >= EAUG) return;
  int s, d;
  if (idx < NE)          { s = ei[idx];              d = ei[NE+idx]; }
  else if (idx < NE+NN)  { int i = idx-NE;           s = i;            d = batch[i]+NN; }
  else if (idx < NE2)    { int i = idx-(NE+NN);      s = batch[i]+NN;  d = i; }
  else                   { int i = idx-NE2;          s = i;            d = i; }
  srcA[idx]=s; dstA[idx]=d;
}

// ---------- CSR build ----------
__global__ void count_k(const int* __restrict__ dstA, int* __restrict__ cnt){
  int e = blockIdx.x*256 + threadIdx.x;
  if (e < EAUG) atomicAdd(&cnt[dstA[e]], 1);
}

__global__ void scan_k(const int* __restrict__ cnt, int* __restrict__ rowptr){
  __shared__ int part[1024];
  int tid = threadIdx.x;
  const int per = (NAUG + 1023) / 1024;
  int base = tid * per;
  int s = 0;
  for (int i=0;i<per;i++){ int idx=base+i; if (idx<NAUG) s += cnt[idx]; }
  part[tid] = s;
  __syncthreads();
  for (int off=1; off<1024; off<<=1){
    int v = (tid>=off) ? part[tid-off] : 0;
    __syncthreads();
    part[tid] += v;
    __syncthreads();
  }
  int run = (tid==0) ? 0 : part[tid-1];
  for (int i=0;i<per;i++){
    int idx=base+i;
    if (idx<NAUG){ rowptr[idx]=run; run += cnt[idx]; }
  }
  if (tid==0) rowptr[NAUG] = EAUG;
}

__global__ void scatter_k(const int* __restrict__ srcA, const int* __restrict__ dstA,
                          const int* __restrict__ rowptr, int* __restrict__ cursor,
                          int* __restrict__ eid, int* __restrict__ esrc,
                          int* __restrict__ epos, int* __restrict__ pdst){
  int e = blockIdx.x*256 + threadIdx.x;
  if (e >= EAUG) return;
  int d = dstA[e];
  int pos = rowptr[d] + atomicAdd(&cursor[d], 1);
  eid[pos]  = e;
  esrc[pos] = srcA[e];
  pdst[pos] = d;
  epos[e]   = pos;
}

// ---------- one-hot padding rows of aug (CSR-permuted, bf16) ----------
__global__ void set_ep_k(const int* __restrict__ epos, unsigned short* __restrict__ aug_b){
  int idx = blockIdx.x*256 + threadIdx.x;
  if (idx >= 2*NN*DD) return;
  int i = idx >> 6, c = idx & 63;
  aug_b[(size_t)epos[NE + i]*DD + c] = (c==0) ? (unsigned short)0x3F80 : (unsigned short)0;
}

// ---------- loop_attr via CSR (sequential aug_b), write via epos ----------
__launch_bounds__(256)
__global__ void loopmean_k(const int* __restrict__ rowptr, const int* __restrict__ eid,
                           const int* __restrict__ epos, unsigned short* __restrict__ aug_b){
  int tid = threadIdx.x;
  int d = blockIdx.x*16 + (tid>>4);
  if (d >= NAUG) return;
  int t4 = (tid & 15)*4;
  int beg = rowptr[d], end = rowptr[d+1];
  float4 s = make_float4(0.f,0.f,0.f,0.f); int n = 0;
  for (int p=beg; p<end; p++){
    int e = eid[p];
    if (e < NE2){
      float4 a = b2f4(*(const ushort4*)(aug_b + (size_t)p*DD + t4));
      s.x += a.x; s.y += a.y; s.z += a.z; s.w += a.w;
      n++;
    }
  }
  float cv = (n < 1) ? 1.f : (float)n;
  *(ushort4*)(aug_b + (size_t)epos[NE2+d]*DD + t4) = f2b4(f4s(s, 1.f/cv));
}

// =====================================================================
// Per-graph CSR message aggregation: 2 blocks/graph, o + local-src in LDS
// =====================================================================
__launch_bounds__(512)
__global__ void msg_graph_k(const float* __restrict__ o, const unsigned short* __restrict__ aug_b,
                            const int* __restrict__ rowptr,
                            const int* __restrict__ esrc, float* __restrict__ aggsum){
  __shared__ __align__(16) float OS[101*72];
  __shared__ unsigned char EL[3072];
  const int g = blockIdx.x >> 1, half = blockIdx.x & 1;
  const int tid = threadIdx.x;
  for (int i = tid; i < 101*16; i += 512){
    int ln = i >> 4, c4 = (i & 15)*4;
    int row = (ln < 100) ? g*100 + ln : NN + g;
    *(float4*)&OS[ln*72 + c4] = *(const float4*)(o + (size_t)row*DD + c4);
  }
  const int baseA = rowptr[g*100];
  const int lenA  = rowptr[g*100 + 100] - baseA;
  const int baseB = rowptr[NN + g];
  const int lenB  = rowptr[NN + g + 1] - baseB;
  const bool useL = (lenA + lenB) <= 3072;
  if (useL){
    for (int i = tid; i < lenA; i += 512){
      int s = esrc[baseA + i];
      EL[i] = (unsigned char)((s >= NN) ? 100 : (s - g*100));
    }
    for (int i = tid; i < lenB; i += 512){
      int s = esrc[baseB + i];
      EL[lenA + i] = (unsigned char)((s >= NN) ? 100 : (s - g*100));
    }
  }
  __syncthreads();
  const int gr = tid >> 4, t4 = (tid & 15)*4;
  const int ld0 = half ? 51 : 0, ld1 = half ? 101 : 51;
  for (int ld = ld0 + gr; ld < ld1; ld += 32){
    int d, pbeg, pend, eofs;
    if (ld < 100){ d = g*100 + ld; pbeg = rowptr[d]; pend = rowptr[d+1]; eofs = -baseA; }
    else         { d = NN + g;     pbeg = baseB;     pend = baseB + lenB; eofs = lenA - baseB; }
    float4 acc = make_float4(0.f,0.f,0.f,0.f);
    for (int p = pbeg; p < pend; p++){
      int ls;
      if (useL) ls = EL[p + eofs];
      else { int s = esrc[p]; ls = (s >= NN) ? 100 : (s - g*100); }
      float4 ov = *(const float4*)&OS[ls*72 + t4];
      float4 ae = b2f4(*(const ushort4*)(aug_b + (size_t)p*DD + t4));
      acc.x += fmaxf(ov.x+ae.x, 0.f) + 1e-7f;
      acc.y += fmaxf(ov.y+ae.y, 0.f) + 1e-7f;
      acc.z += fmaxf(ov.z+ae.z, 0.f) + 1e-7f;
      acc.w += fmaxf(ov.w+ae.w, 0.f) + 1e-7f;
    }
    *(float4*)(aggsum + (size_t)d*DD + t4) = acc;
  }
}

__global__ void copy_o_xin_k(const float* __restrict__ o, float* __restrict__ xin){
  int idx = blockIdx.x*256 + threadIdx.x;
  if (idx >= NAUG*DD) return;
  int n = idx >> 6, c = idx & 63;
  xin[(size_t)n*HC + c] = o[idx];
}

// =====================================================================
// Edge-parallel logits: lg[p] = 0.125*(q[d]·k[s] + qe[d]·ae[p]) per head
// =====================================================================
__launch_bounds__(512)
__global__ void scoredot_k(const float* __restrict__ qkvs, const float* __restrict__ qe,
                           const unsigned short* __restrict__ aug_b,
                           const int* __restrict__ pdst, const int* __restrict__ esrc,
                           float2* __restrict__ lg){
  int p = blockIdx.x*32 + (threadIdx.x >> 4);
  if (p >= EAUG) return;
  int t4 = (threadIdx.x & 15)*4;
  int d = pdst[p], s = esrc[p];
  const float* qr = qkvs + (size_t)d*512;
  const float* kr = qkvs + (size_t)s*512 + 128;
  float4 q0  = *(const float4*)(qr + t4);
  float4 q1  = *(const float4*)(qr + 64 + t4);
  float4 qe0 = *(const float4*)(qe + (size_t)d*HC + t4);
  float4 qe1 = *(const float4*)(qe + (size_t)d*HC + 64 + t4);
  float4 k0  = *(const float4*)(kr + t4);
  float4 k1  = *(const float4*)(kr + 64 + t4);
  float4 ae  = b2f4(*(const ushort4*)(aug_b + (size_t)p*DD + t4));
  float p0 = d4(q0,k0) + d4(qe0,ae);
  float p1 = d4(q1,k1) + d4(qe1,ae);
  p0 += __shfl_xor(p0,8); p0 += __shfl_xor(p0,4); p0 += __shfl_xor(p0,2); p0 += __shfl_xor(p0,1);
  p1 += __shfl_xor(p1,8); p1 += __shfl_xor(p1,4); p1 += __shfl_xor(p1,2); p1 += __shfl_xor(p1,1);
  if ((threadIdx.x & 15) == 0) lg[p] = make_float2(p0*0.125f, p1*0.125f);
}

// =====================================================================
// Attention-lite: per half-graph, V in LDS, online softmax over logit
// stream -> t1 (normalized), per-dst m and 1/(l+eps)
// =====================================================================
__launch_bounds__(512)
__global__ void attn_lite_k(const float* __restrict__ qkvs, const float2* __restrict__ lg,
                            const int* __restrict__ rowptr, const int* __restrict__ esrc,
                            float* __restrict__ t1, float2* __restrict__ m2,
                            float2* __restrict__ linv2){
  __shared__ __align__(16) unsigned short VS[101*128];   // 25.9 KB
  __shared__ unsigned char EL[3072];
  const int g = blockIdx.x >> 1, half = blockIdx.x & 1;
  const int tid = threadIdx.x;
  for (int i = tid; i < 101*32; i += 512){
    int ln = i >> 5, c4 = (i & 31)*4;
    int row = (ln < 100) ? g*100 + ln : NN + g;
    float4 v = *(const float4*)(qkvs + (size_t)row*512 + 256 + c4);
    *(ushort4*)&VS[ln*128 + c4] = f2b4(v);
  }
  const int baseA = rowptr[g*100];
  const int lenA  = rowptr[g*100 + 100] - baseA;
  const int baseB = rowptr[NN + g];
  const int lenB  = rowptr[NN + g + 1] - baseB;
  const bool useL = (lenA + lenB) <= 3072;
  if (useL){
    for (int i = tid; i < lenA; i += 512){
      int s = esrc[baseA + i];
      EL[i] = (unsigned char)((s >= NN) ? 100 : (s - g*100));
    }
    for (int i = tid; i < lenB; i += 512){
      int s = esrc[baseB + i];
      EL[lenA + i] = (unsigned char)((s >= NN) ? 100 : (s - g*100));
    }
  }
  __syncthreads();
  const int gr = tid >> 4, t4 = (tid & 15)*4;
  const int ld0 = half ? 51 : 0, ld1 = half ? 101 : 51;
  for (int ld = ld0 + gr; ld < ld1; ld += 32){
    int d, pbeg, pend, eofs;
    if (ld < 100){ d = g*100 + ld; pbeg = rowptr[d]; pend = rowptr[d+1]; eofs = -baseA; }
    else         { d = NN + g;     pbeg = baseB;     pend = baseB + lenB; eofs = lenA - baseB; }
    float m0=-1e30f, m1=-1e30f, l0=0.f, l1=0.f;
    float4 a0 = make_float4(0.f,0.f,0.f,0.f), a1 = a0;
    float2 lv = lg[pbeg];
    for (int p = pbeg; p < pend; p++){
      float2 nxt = (p+1 < pend) ? lg[p+1] : make_float2(0.f,0.f);
      int ls;
      if (useL) ls = EL[p + eofs];
      else { int s = esrc[p]; ls = (s >= NN) ? 100 : (s - g*100); }
      const unsigned short* vr = &VS[ls*128];
      float4 v0 = b2f4(*(const ushort4*)(vr + t4));
      float4 v1 = b2f4(*(const ushort4*)(vr + 64 + t4));
      float nm0 = fmaxf(m0, lv.x);
      float sc0 = __expf(m0 - nm0);
      float e0  = __expf(lv.x - nm0);
      l0 = l0*sc0 + e0; a0 = f4ab(a0, sc0, v0, e0); m0 = nm0;
      float nm1 = fmaxf(m1, lv.y);
      float sc1 = __expf(m1 - nm1);
      float e1  = __expf(lv.y - nm1);
      l1 = l1*sc1 + e1; a1 = f4ab(a1, sc1, v1, e1); m1 = nm1;
      lv = nxt;
    }
    float i0 = 1.f/(l0 + 1e-16f), i1 = 1.f/(l1 + 1e-16f);
    *(float4*)(t1 + (size_t)d*HC + t4)      = f4s(a0, i0);
    *(float4*)(t1 + (size_t)d*HC + 64 + t4) = f4s(a1, i1);
    if ((tid & 15) == 0){
      m2[d]    = make_float2(m0, m1);
      linv2[d] = make_float2(i0, i1);
    }
  }
}

// =====================================================================
// wsum: wbuf[d] = sum_p exp(lg[p]-m[d])*linv[d] * ae[p]  (CSR groups)
// =====================================================================
__launch_bounds__(256)
__global__ void wsum_k(const unsigned short* __restrict__ aug_b, const float2* __restrict__ lg,
                       const float2* __restrict__ m2, const float2* __restrict__ linv2,
                       const int* __restrict__ rowptr, float* __restrict__ wbuf){
  int tid = threadIdx.x;
  int d = blockIdx.x*16 + (tid>>4);
  if (d >= NAUG) return;
  int t4 = (tid & 15)*4;
  float2 m = m2[d], li = linv2[d];
  float4 w0 = make_float4(0.f,0.f,0.f,0.f), w1 = w0;
  int beg = rowptr[d], end = rowptr[d+1];
  for (int p = beg; p < end; p++){
    float2 lv = lg[p];
    float4 ae = b2f4(*(const ushort4*)(aug_b + (size_t)p*DD + t4));
    float a0 = __expf(lv.x - m.x) * li.x;
    float a1 = __expf(lv.y - m.y) * li.y;
    w0.x += a0*ae.x; w0.y += a0*ae.y; w0.z += a0*ae.z; w0.w += a0*ae.w;
    w1.x += a1*ae.x; w1.y += a1*ae.y; w1.z += a1*ae.z; w1.w += a1*ae.w;
  }
  *(float4*)(wbuf + (size_t)d*HC + t4)      = w0;
  *(float4*)(wbuf + (size_t)d*HC + 64 + t4) = w1;
}

// ---------- per-graph layernorm ----------
__global__ void ln_k(const float* __restrict__ y, float* __restrict__ o){
  int g = blockIdx.x, tid = threadIdx.x;
  float sum=0.f, ss=0.f;
  for (int i=tid; i<101*64; i+=256){
    int nd=i>>6, c=i&63;
    int row = (nd<100) ? g*100+nd : NN+g;
    float v = y[(size_t)row*DD + c];
    sum += v; ss += v*v;
  }
  #pragma unroll
  for (int off=32; off; off>>=1){ sum += __shfl_xor(sum, off); ss += __shfl_xor(ss, off); }
  __shared__ float s1[4], s2[4];
  if ((tid&63)==0){ s1[tid>>6]=sum; s2[tid>>6]=ss; }
  __syncthreads();
  sum = s1[0]+s1[1]+s1[2]+s1[3];
  ss  = s2[0]+s2[1]+s2[2]+s2[3];
  const float inv = 1.f/6464.f;
  float mean = sum*inv;
  float var  = ss*inv - mean*mean;
  float rstd = rsqrtf(var + 1e-5f);
  for (int i=tid; i<101*64; i+=256){
    int nd=i>>6, c=i&63;
    int row = (nd<100) ? g*100+nd : NN+g;
    o[(size_t)row*DD + c] = (y[(size_t)row*DD + c] - mean)*rstd;
  }
}

__global__ void copy_c_o_k(const float* __restrict__ c_emb, float* __restrict__ o){
  int idx = blockIdx.x*256 + threadIdx.x;
  if (idx >= NG*DD) return;
  o[(size_t)NN*DD + idx] = c_emb[idx];
}

// ---------- final outputs ----------
__global__ void glob_k(const float* __restrict__ o, const float* __restrict__ c_emb,
                       float* __restrict__ gout){
  int g = blockIdx.x, c = threadIdx.x;
  float acc = 0.f;
  for (int t=0;t<100;t++) acc += o[(size_t)(g*100+t)*DD + c];
  gout[(size_t)g*192 + c]       = acc / 100.f;
  gout[(size_t)g*192 + 64 + c]  = o[(size_t)(NN+g)*DD + c];
  gout[(size_t)g*192 + 128 + c] = c_emb[(size_t)g*DD + c];
}
__global__ void ofinal_k(const float* __restrict__ o, const float* __restrict__ c_emb,
                         const int* __restrict__ batch, float* __restrict__ out){
  int idx = blockIdx.x*256 + threadIdx.x;
  if (idx >= NN*HC) return;
  int n = idx>>7, j = idx&127;
  out[idx] = (j<64) ? o[(size_t)n*DD + j] : c_emb[(size_t)batch[n]*DD + (j-64)];
}

static inline int cdiv(int a, int b){ return (a+b-1)/b; }

static inline void gemm_mfma(int N, const float* A, const float* A2, int M, int K, int lda,
                             const unsigned short* Wt, const float* bias, int act,
                             const float* res, const float* res2, int rstride,
                             float* out, int ostride, hipStream_t st){
  int KC = (K > 128) ? 128 : K;
  int KPc = KC + 8;
  size_t sh = (size_t)(N*KPc + 64*KPc) * 2;
  int grid = cdiv(M, 64);
  if (N == 64)
    gemm_mfma_k<64><<<grid,256,sh,st>>>(A,A2,M,K,lda,Wt,bias,act,res,res2,rstride,out,ostride);
  else if (N == 128)
    gemm_mfma_k<128><<<grid,256,sh,st>>>(A,A2,M,K,lda,Wt,bias,act,res,res2,rstride,out,ostride);
  else
    gemm_mfma_k<256><<<grid,256,sh,st>>>(A,A2,M,K,lda,Wt,bias,act,res,res2,rstride,out,ostride);
}

extern "C" void kernel_launch(void* const* d_in, const int* in_sizes, int n_in,
                              void* d_out, int out_size, void* d_ws, size_t ws_size,
                              hipStream_t stream){
  (void)in_sizes; (void)n_in; (void)out_size;
  const float* x         = (const float*)d_in[0];
  const float* edge_attr = (const float*)d_in[1];
  const float* cond      = (const float*)d_in[2];
  const int*   edge_index= (const int*)  d_in[3];
  const int*   batch     = (const int*)  d_in[4];
  const float* xW1=(const float*)d_in[5],  *xb1=(const float*)d_in[6],
             * xW2=(const float*)d_in[7],  *xb2=(const float*)d_in[8],
             * xW3=(const float*)d_in[9],  *xb3=(const float*)d_in[10];
  const float* eW1=(const float*)d_in[11], *eb1=(const float*)d_in[12],
             * eW2=(const float*)d_in[13], *eb2=(const float*)d_in[14],
             * eW3=(const float*)d_in[15], *eb3=(const float*)d_in[16];
  const float* cW1=(const float*)d_in[17], *cb1=(const float*)d_in[18],
             * cW2=(const float*)d_in[19], *cb2=(const float*)d_in[20],
             * cW3=(const float*)d_in[21], *cb3=(const float*)d_in[22];
  const float* gen_W=(const float*)d_in[23];
  const float* trWq=(const float*)d_in[24], *trbq=(const float*)d_in[25];
  const float* trWk=(const float*)d_in[26], *trbk=(const float*)d_in[27];
  const float* trWv=(const float*)d_in[28], *trbv=(const float*)d_in[29];
  const float* trWe=(const float*)d_in[30];
  const float* trWs=(const float*)d_in[31], *trbs=(const float*)d_in[32];
  const float* linW=(const float*)d_in[33], *linb=(const float*)d_in[34];
  const float* ffW1=(const float*)d_in[35], *ffb1=(const float*)d_in[36];
  const float* ffW2=(const float*)d_in[37], *ffb2=(const float*)d_in[38];
  float* out = (float*)d_out;

  // ---- workspace carve-up (floats) ----
  float* ws = (float*)d_ws;
  size_t off = 0;
  auto alloc = [&](size_t n)->float*{ float* p = ws + off; off += (n + 63) & ~(size_t)63; return p; };
  int*      srcA  = (int*)alloc(EAUG);
  int*      dstA  = (int*)alloc(EAUG);
  int*      cnt   = (int*)alloc(NAUG);
  int*      rowptr= (int*)alloc(NAUG+1);
  int*      cursor= (int*)alloc(NAUG);
  int*      eid   = (int*)alloc(EAUG);
  int*      esrc  = (int*)alloc(EAUG);
  int*      epos  = (int*)alloc(EAUG);
  int*      pdst  = (int*)alloc(EAUG);
  unsigned short* aug_b = (unsigned short*)alloc((size_t)EAUG*DD/2);  // bf16 CSR-permuted
  float*    o     = alloc((size_t)NAUG*DD);
  float*    c_emb = alloc((size_t)NG*DD);
  float*    ybuf  = alloc((size_t)NAUG*DD);
  float*    aggsum= alloc((size_t)NAUG*DD);
  float*    xin   = alloc((size_t)NAUG*HC);
  float*    xqkvs = alloc((size_t)NAUG*512);
  float*    qeb   = alloc((size_t)NAUG*HC);
  float*    toutb = alloc((size_t)NAUG*HC);
  float*    t1    = alloc((size_t)NAUG*HC);
  float*    wbuf  = alloc((size_t)NAUG*HC);
  float*    ffh   = alloc((size_t)NAUG*256);
  float2*   lgb   = (float2*)alloc((size_t)EAUG*2);
  float2*   m2v   = (float2*)alloc((size_t)NAUG*2);
  float2*   li2v  = (float2*)alloc((size_t)NAUG*2);
  unsigned short* warena = (unsigned short*)alloc(222720);   // 445440 bf16 weights
  if (off*sizeof(float) > ws_size) return;

  const unsigned short* wptr[45];
  int wblk = 0;
  { size_t woff = 0;
    for (int j = 0; j < 45; j++){
      wptr[j] = warena + woff;
      int e = WTAB_H[j][3]*WTAB_H[j][4];
      woff += (size_t)e;
      wblk += cdiv(e, 256);
    } }

  // ---- weight conversion (one launch) ----
  WPtrs wp;
  wp.p[0]=trWq; wp.p[1]=trWk; wp.p[2]=trWv; wp.p[3]=trWs; wp.p[4]=gen_W;
  wp.p[5]=linW; wp.p[6]=ffW1; wp.p[7]=ffW2; wp.p[8]=trWe;
  wp.p[9]=xW1; wp.p[10]=xW2; wp.p[11]=xW3;
  wp.p[12]=eW1; wp.p[13]=eW2; wp.p[14]=eW3;
  wp.p[15]=cW1; wp.p[16]=cW2; wp.p[17]=cW3;
  wconv_all_k<<<wblk,256,0,stream>>>(wp, warena);

  // ---- setup: edges + CSR (+ epos/pdst) ----
  build_edges_k<<<cdiv(EAUG,256),256,0,stream>>>(edge_index, batch, srcA, dstA);
  hipMemsetAsync(cnt, 0, sizeof(int)*NAUG, stream);
  hipMemsetAsync(cursor, 0, sizeof(int)*NAUG, stream);
  count_k<<<cdiv(EAUG,256),256,0,stream>>>(dstA, cnt);
  scan_k<<<1,1024,0,stream>>>(cnt, rowptr);
  scatter_k<<<cdiv(EAUG,256),256,0,stream>>>(srcA, dstA, rowptr, cursor, eid, esrc, epos, pdst);

  // ---- input MLPs (edge MLP -> bf16 CSR-permuted) + pads / loop-attr ----
  mlp3_mfma_k<<<cdiv(NN,64),256,0,stream>>>(x,        NN, 32, wptr[36],wptr[37],wptr[38], xb1,xb2,xb3, nullptr, o,     nullptr);
  mlp3_mfma_k<<<cdiv(NG,64),256,0,stream>>>(cond,     NG, 32, wptr[42],wptr[43],wptr[44], cb1,cb2,cb3, nullptr, c_emb, nullptr);
  mlp3_mfma_k<<<cdiv(NE,64),256,0,stream>>>(edge_attr,NE, 16, wptr[39],wptr[40],wptr[41], eb1,eb2,eb3, epos,    nullptr, aug_b);
  set_ep_k<<<cdiv(2*NN*DD,256),256,0,stream>>>(epos, aug_b);
  loopmean_k<<<cdiv(NAUG,16),256,0,stream>>>(rowptr, eid, epos, aug_b);
  copy_c_o_k<<<cdiv(NG*DD,256),256,0,stream>>>(c_emb, o);

  // ---- layers ----
  for (int L=0; L<3; L++){
    const float* lb_i = linb + (size_t)L*DD;
    const float* f1b  = ffb1 + (size_t)L*256;
    const float* f2b  = ffb2 + (size_t)L*DD;
    const unsigned short* genT = wptr[12+L], *linT = wptr[15+L], *ff1T = wptr[18+L], *ff2T = wptr[21+L];
    PW4 pw4; pw4.w[0]=wptr[0+L]; pw4.w[1]=wptr[3+L]; pw4.w[2]=wptr[6+L]; pw4.w[3]=wptr[9+L];
    pw4.b[0]=trbq+(size_t)L*HC; pw4.b[1]=trbk+(size_t)L*HC;
    pw4.b[2]=trbv+(size_t)L*HC; pw4.b[3]=trbs+(size_t)L*HC;
    PW2 pwE; pwE.w[0]=wptr[24+2*L]; pwE.w[1]=wptr[25+2*L];
    PW2 pwT; pwT.w[0]=wptr[30+2*L]; pwT.w[1]=wptr[31+2*L];

    msg_graph_k<<<2*NG,512,0,stream>>>(o, aug_b, rowptr, esrc, aggsum);
    copy_o_xin_k<<<cdiv(NAUG*DD,256),256,0,stream>>>(o, xin);
    gemm_mfma( 64, aggsum, o, NAUG, 64, 64, genT, nullptr, 0, nullptr, nullptr, 0, xin+64, HC, stream);
    qkvs4_k<<<dim3(cdiv(NAUG,64),4),256,0,stream>>>(xin, NAUG, pw4, xqkvs);
    qe2_k<<<dim3(cdiv(NAUG,64),2),256,0,stream>>>(xqkvs, NAUG, pwE, qeb);
    scoredot_k<<<cdiv(EAUG,32),512,0,stream>>>(xqkvs, qeb, aug_b, pdst, esrc, lgb);
    attn_lite_k<<<2*NG,512,0,stream>>>(xqkvs, lgb, rowptr, esrc, t1, m2v, li2v);
    wsum_k<<<cdiv(NAUG,16),256,0,stream>>>(aug_b, lgb, m2v, li2v, rowptr, wbuf);
    tout2_k<<<dim3(cdiv(NAUG,64),2),256,0,stream>>>(wbuf, NAUG, pwT, t1, xqkvs, toutb);
    gemm_mfma( 64, toutb, nullptr, NAUG, 128, 128, linT, lb_i, 0, o, nullptr, DD, ybuf, DD, stream);
    ln_k<<<NG,256,0,stream>>>(ybuf, o);
    gemm_mfma(256, o,   nullptr, NAUG,  64,  64, ff1T, f1b, 1, nullptr, nullptr, 0, ffh, 256, stream);
    gemm_mfma( 64, ffh, nullptr, NAUG, 256, 256, ff2T, f2b, 0, o, nullptr, DD, ybuf, DD, stream);
    ln_k<<<NG,256,0,stream>>>(ybuf, o);
  }

  // ---- outputs ----
  glob_k<<<NG,64,0,stream>>>(o, c_emb, out + (size_t)NN*HC);
  ofinal_k<<<cdiv(NN*HC,256),256,0,stream>>>(o, c_emb, batch, out);
}

// Round 9
// 1316.432 us; speedup vs baseline: 1.0161x; 1.0161x over previous
//
#include <hip/hip_runtime.h>
#include <cstddef>

#define NN   20000          // real nodes
#define NG   200            // graphs / virtual nodes
#define NE   320000         // original edges
#define NAUG 20200          // NN + NG
#define NE2  360000         // NE + 2*NN  (edges before self-loops)
#define EAUG 380200         // NE2 + NAUG
#define DD   64             // NUM_EMB
#define HC   128            // HEADS * NUM_EMB
#define QS   640            // xqkvs row stride: [q|k|v|xs|qe]

typedef float  f32x4 __attribute__((ext_vector_type(4)));
typedef short  s16x8 __attribute__((ext_vector_type(8)));

static __device__ __forceinline__ unsigned short bf16r(float f){
  unsigned u = __float_as_uint(f);
  u += 0x7FFFu + ((u >> 16) & 1u);
  return (unsigned short)(u >> 16);
}
static __device__ __forceinline__ float4 b2f4(ushort4 u){
  return make_float4(__uint_as_float((unsigned)u.x << 16),
                     __uint_as_float((unsigned)u.y << 16),
                     __uint_as_float((unsigned)u.z << 16),
                     __uint_as_float((unsigned)u.w << 16));
}
static __device__ __forceinline__ ushort4 f2b4(float4 v){
  ushort4 s; s.x=bf16r(v.x); s.y=bf16r(v.y); s.z=bf16r(v.z); s.w=bf16r(v.w); return s;
}
static __device__ __forceinline__ float d4(float4 a, float4 b){
  return a.x*b.x + a.y*b.y + a.z*b.z + a.w*b.w;
}
static __device__ __forceinline__ float4 f4a(float4 a, float4 b, float t){
  return make_float4(a.x + b.x*t, a.y + b.y*t, a.z + b.z*t, a.w + b.w*t);
}
static __device__ __forceinline__ float4 f4s(float4 a, float s){
  return make_float4(a.x*s, a.y*s, a.z*s, a.w*s);
}

// =====================================================================
// Weight pre-conversion: fp32 -> bf16, transposed to Bt[n][k], stride KP=K+8
// {srcIdx, mode, Ksrc, N, KP, stride, soff}; mode0 transpose, mode1 direct
// =====================================================================
#define WTAB_INIT { \
  {0,0,128,128,136,128,0},{0,0,128,128,136,128,16384},{0,0,128,128,136,128,32768}, \
  {1,0,128,128,136,128,0},{1,0,128,128,136,128,16384},{1,0,128,128,136,128,32768}, \
  {2,0,128,128,136,128,0},{2,0,128,128,136,128,16384},{2,0,128,128,136,128,32768}, \
  {3,0,128,128,136,128,0},{3,0,128,128,136,128,16384},{3,0,128,128,136,128,32768}, \
  {4,0,64,64,72,64,0},{4,0,64,64,72,64,4096},{4,0,64,64,72,64,8192}, \
  {5,0,128,64,136,64,0},{5,0,128,64,136,64,8192},{5,0,128,64,136,64,16384}, \
  {6,0,64,256,72,256,0},{6,0,64,256,72,256,16384},{6,0,64,256,72,256,32768}, \
  {7,0,256,64,264,64,0},{7,0,256,64,264,64,16384},{7,0,256,64,264,64,32768}, \
  {8,0,64,64,72,128,0},{8,0,64,64,72,128,64},{8,0,64,64,72,128,8192},{8,0,64,64,72,128,8256},{8,0,64,64,72,128,16384},{8,0,64,64,72,128,16448}, \
  {9,0,32,64,40,64,0},{10,0,64,64,72,64,0},{11,0,64,64,72,64,0}, \
  {12,0,16,64,40,64,0},{13,0,64,64,72,64,0},{14,0,64,64,72,64,0}, \
  {15,0,32,64,40,64,0},{16,0,64,64,72,64,0},{17,0,64,64,72,64,0} }

static const int WTAB_H[39][7] = WTAB_INIT;
__device__ static const int WTAB_D[39][7] = WTAB_INIT;

struct WPtrs { const float* p[18]; };

__global__ void wconv_all_k(WPtrs wp, unsigned short* __restrict__ outbase){
  int b = blockIdx.x;
  int acc = 0; unsigned ooff = 0;
  #pragma unroll 1
  for (int j = 0; j < 39; j++){
    int e  = WTAB_D[j][3] * WTAB_D[j][4];
    int nb = (e + 255) >> 8;
    if (b < acc + nb){
      int idx = (b - acc)*256 + threadIdx.x;
      if (idx < e){
        int KP = WTAB_D[j][4];
        int n = idx / KP, k = idx % KP;
        float v = 0.f;
        if (k < WTAB_D[j][2]){
          const float* s = wp.p[WTAB_D[j][0]];
          int st = WTAB_D[j][5], so = WTAB_D[j][6];
          v = (WTAB_D[j][1] == 0) ? s[(size_t)so + (size_t)k*st + n]
                                  : s[(size_t)so + (size_t)n*st + k];
        }
        outbase[ooff + idx] = bf16r(v);
      }
      return;
    }
    acc += nb; ooff += (unsigned)e;
  }
}

// =====================================================================
// Combined qe weight: Wqe[i, h*64+d] = sum_c Wq[i,h*64+c]*We[d,h*64+c]
// stored transposed bf16 [n=h*64+d][k=i], KP=136; bias bqe[n]
// =====================================================================
__global__ void qecomb_k(const float* __restrict__ trWq, const float* __restrict__ trbq,
                         const float* __restrict__ trWe,
                         unsigned short* __restrict__ qweb, float* __restrict__ bqeb){
  int L = blockIdx.y;
  int n = blockIdx.x;            // h*64+d
  int i = threadIdx.x;           // 0..127
  int h = n >> 6, d = n & 63;
  const float* Wq = trWq + (size_t)L*128*128;
  const float* We = trWe + (size_t)L*64*128;
  float acc = 0.f;
  for (int c = 0; c < 64; c++)
    acc += Wq[(size_t)i*128 + h*64 + c] * We[(size_t)d*128 + h*64 + c];
  qweb[(size_t)L*128*136 + n*136 + i] = bf16r(acc);
  if (i < 8) qweb[(size_t)L*128*136 + n*136 + 128 + i] = 0;
  if (i == 0){
    const float* bq = trbq + (size_t)L*128;
    float b = 0.f;
    for (int c = 0; c < 64; c++) b += bq[h*64 + c] * We[(size_t)d*128 + h*64 + c];
    bqeb[L*128 + n] = b;
  }
}

// =====================================================================
// Generic MFMA GEMM (template N): out = act(A(+A2) @ W + bias) + res(+res2)
// =====================================================================
template<int NT>
__launch_bounds__(256)
__global__ void gemm_mfma_k(const float* __restrict__ A, const float* __restrict__ A2,
                            int M, int K, int lda,
                            const unsigned short* __restrict__ WtG,
                            const float* __restrict__ bias, int act,
                            const float* __restrict__ res, const float* __restrict__ res2,
                            int rstride, float* __restrict__ out, int ostride){
  extern __shared__ unsigned short smem[];
  const int KC  = (K > 128) ? 128 : K;
  const int KPc = KC + 8;
  const int KP  = K + 8;
  unsigned short* Wts  = smem;            // NT * KPc
  unsigned short* Asub = smem + NT*KPc;   // 64 * KPc
  const int tid = threadIdx.x;
  const int wid = tid >> 6, lane = tid & 63;
  const int lrow = lane & 15, quad = lane >> 4;
  const int m0 = blockIdx.x * 64;
  f32x4 acc[NT/16];
  #pragma unroll
  for (int t = 0; t < NT/16; t++) acc[t] = (f32x4){0.f,0.f,0.f,0.f};

  for (int k0 = 0; k0 < K; k0 += KC){
    const int wv = NT*KPc/8, wrow = KPc/8;
    for (int i = tid; i < wv; i += 256){
      int n = i / wrow, c8 = i % wrow;
      *(uint4*)&Wts[n*KPc + c8*8] = *(const uint4*)&WtG[(size_t)n*KP + k0 + c8*8];
    }
    const int av = 64*KC/4, arow = KC/4;
    for (int i = tid; i < av; i += 256){
      int r = i / arow, c4i = i % arow;
      int m = m0 + r, k = k0 + c4i*4;
      float4 v = make_float4(0.f,0.f,0.f,0.f);
      if (m < M){
        v = *(const float4*)(A + (size_t)m*lda + k);
        if (A2){ float4 w = *(const float4*)(A2 + (size_t)m*lda + k);
                 v.x += w.x; v.y += w.y; v.z += w.z; v.w += w.w; }
      }
      *(ushort4*)&Asub[r*KPc + c4i*4] = f2b4(v);
    }
    __syncthreads();
    const int ksteps = KC >> 5;
    for (int ks = 0; ks < ksteps; ks++){
      s16x8 a = *(const s16x8*)&Asub[(wid*16 + lrow)*KPc + ks*32 + quad*8];
      #pragma unroll
      for (int nt = 0; nt < NT/16; nt++){
        s16x8 b = *(const s16x8*)&Wts[(nt*16 + lrow)*KPc + ks*32 + quad*8];
        acc[nt] = __builtin_amdgcn_mfma_f32_16x16x32_bf16(a, b, acc[nt], 0, 0, 0);
      }
    }
    __syncthreads();
  }

  const int mb = m0 + wid*16 + quad*4;
  #pragma unroll
  for (int nt = 0; nt < NT/16; nt++){
    int n = nt*16 + lrow;
    #pragma unroll
    for (int r = 0; r < 4; r++){
      int m = mb + r;
      if (m < M){
        float v = acc[nt][r];
        if (bias) v += bias[n];
        if (act)  v = v > 0.f ? v : 0.01f*v;
        if (res)  v += res [(size_t)m*rstride + n];
        if (res2) v += res2[(size_t)m*rstride + n];
        out[(size_t)m*ostride + n] = v;
      }
    }
  }
}

// =====================================================================
// Batched QKVS+QE GEMM: grid.y in [0,5); out[m, y*128 + n], ostride QS
// =====================================================================
struct PW5 { const unsigned short* w[5]; const float* b[5]; };

__launch_bounds__(256)
__global__ void qkvs5_k(const float* __restrict__ A, int M, PW5 pw,
                        float* __restrict__ out){
  __shared__ __align__(16) unsigned short Wts[128*136];
  __shared__ __align__(16) unsigned short Asub[64*136];
  const unsigned short* WtG = pw.w[blockIdx.y];
  const float* bias = pw.b[blockIdx.y];
  const int tid = threadIdx.x;
  const int wid = tid >> 6, lane = tid & 63;
  const int lrow = lane & 15, quad = lane >> 4;
  const int m0 = blockIdx.x * 64;
  for (int i = tid; i < 128*17; i += 256){
    int n = i/17, c8 = i%17;
    *(uint4*)&Wts[n*136 + c8*8] = *(const uint4*)&WtG[(size_t)n*136 + c8*8];
  }
  for (int i = tid; i < 64*32; i += 256){
    int r = i >> 5, c4 = (i & 31)*4;
    int m = m0 + r;
    float4 v = make_float4(0.f,0.f,0.f,0.f);
    if (m < M) v = *(const float4*)(A + (size_t)m*128 + c4);
    *(ushort4*)&Asub[r*136 + c4] = f2b4(v);
  }
  __syncthreads();
  f32x4 acc[8];
  #pragma unroll
  for (int t=0;t<8;t++) acc[t] = (f32x4){0.f,0.f,0.f,0.f};
  #pragma unroll
  for (int ks = 0; ks < 4; ks++){
    s16x8 a = *(const s16x8*)&Asub[(wid*16 + lrow)*136 + ks*32 + quad*8];
    #pragma unroll
    for (int nt = 0; nt < 8; nt++){
      s16x8 b = *(const s16x8*)&Wts[(nt*16 + lrow)*136 + ks*32 + quad*8];
      acc[nt] = __builtin_amdgcn_mfma_f32_16x16x32_bf16(a, b, acc[nt], 0, 0, 0);
    }
  }
  const int mb = m0 + wid*16 + quad*4;
  const int yoff = blockIdx.y*128;
  #pragma unroll
  for (int nt = 0; nt < 8; nt++){
    int n = nt*16 + lrow;
    #pragma unroll
    for (int r = 0; r < 4; r++){
      int m = mb + r;
      if (m < M) out[(size_t)m*QS + yoff + n] = acc[nt][r] + bias[n];
    }
  }
}

// =====================================================================
// Batched per-head 64x64 GEMM (tout) — grid.y = head
// =====================================================================
struct PW2 { const unsigned short* w[2]; };

__launch_bounds__(256)
__global__ void tout2_k(const float* __restrict__ wv, int M, PW2 pw,
                        const float* __restrict__ t1, const float* __restrict__ qkvs,
                        float* __restrict__ tout){
  __shared__ __align__(16) unsigned short Wts[64*72];
  __shared__ __align__(16) unsigned short Asub[64*72];
  const unsigned short* WtG = pw.w[blockIdx.y];
  const int tid = threadIdx.x;
  const int wid = tid >> 6, lane = tid & 63;
  const int lrow = lane & 15, quad = lane >> 4;
  const int m0 = blockIdx.x * 64;
  const int yoff = blockIdx.y * 64;
  for (int i = tid; i < 64*9; i += 256){
    int n = i/9, c8 = i%9;
    *(uint4*)&Wts[n*72 + c8*8] = *(const uint4*)&WtG[(size_t)n*72 + c8*8];
  }
  for (int i = tid; i < 64*16; i += 256){
    int r = i >> 4, c4 = (i & 15)*4;
    int m = m0 + r;
    float4 v = make_float4(0.f,0.f,0.f,0.f);
    if (m < M) v = *(const float4*)(wv + (size_t)m*HC + yoff + c4);
    *(ushort4*)&Asub[r*72 + c4] = f2b4(v);
  }
  __syncthreads();
  f32x4 acc[4];
  #pragma unroll
  for (int t=0;t<4;t++) acc[t] = (f32x4){0.f,0.f,0.f,0.f};
  #pragma unroll
  for (int ks = 0; ks < 2; ks++){
    s16x8 a = *(const s16x8*)&Asub[(wid*16 + lrow)*72 + ks*32 + quad*8];
    #pragma unroll
    for (int nt = 0; nt < 4; nt++){
      s16x8 b = *(const s16x8*)&Wts[(nt*16 + lrow)*72 + ks*32 + quad*8];
      acc[nt] = __builtin_amdgcn_mfma_f32_16x16x32_bf16(a, b, acc[nt], 0, 0, 0);
    }
  }
  const int mb = m0 + wid*16 + quad*4;
  #pragma unroll
  for (int nt = 0; nt < 4; nt++){
    int n = nt*16 + lrow;
    #pragma unroll
    for (int r = 0; r < 4; r++){
      int m = mb + r;
      if (m < M)
        tout[(size_t)m*HC + yoff + n] = acc[nt][r]
          + t1[(size_t)m*HC + yoff + n] + qkvs[(size_t)m*QS + 384 + yoff + n];
    }
  }
}

// =====================================================================
// Fused 3-layer MLP via MFMA; fp32 out OR bf16 out with row permutation
// =====================================================================
__launch_bounds__(256)
__global__ void mlp3_mfma_k(const float* __restrict__ X, int M, int Din,
                            const unsigned short* __restrict__ w1t,
                            const unsigned short* __restrict__ w2t,
                            const unsigned short* __restrict__ w3t,
                            const float* __restrict__ b1, const float* __restrict__ b2,
                            const float* __restrict__ b3,
                            const int* __restrict__ perm, float* __restrict__ out,
                            unsigned short* __restrict__ outb){
  __shared__ __align__(16) unsigned short W1s[64*40], W2s[64*72], W3s[64*72];
  __shared__ __align__(16) unsigned short xs[64*40], hs[64*72];
  __shared__ float bsh[192];
  const int tid = threadIdx.x;
  for (int i = tid; i < 320; i += 256)  *(uint4*)&W1s[i*8] = *(const uint4*)&w1t[i*8];
  for (int i = tid; i < 576; i += 256){ *(uint4*)&W2s[i*8] = *(const uint4*)&w2t[i*8];
                                        *(uint4*)&W3s[i*8] = *(const uint4*)&w3t[i*8]; }
  if (tid < 64){ bsh[tid] = b1[tid]; bsh[64+tid] = b2[tid]; bsh[128+tid] = b3[tid]; }
  const int m0 = blockIdx.x * 64;
  for (int i = tid; i < 512; i += 256){
    int r = i >> 3, c4 = (i & 7) * 4;
    int m = m0 + r;
    float4 v = make_float4(0.f,0.f,0.f,0.f);
    if (m < M && c4 < Din) v = *(const float4*)(X + (size_t)m*Din + c4);
    *(ushort4*)&xs[r*40 + c4] = f2b4(v);
  }
  __syncthreads();
  const int wid = tid >> 6, lane = tid & 63;
  const int lrow = lane & 15, quad = lane >> 4;
  f32x4 acc[4];

  #pragma unroll
  for (int t = 0; t < 4; t++) acc[t] = (f32x4){0.f,0.f,0.f,0.f};
  {
    s16x8 a = *(const s16x8*)&xs[(wid*16 + lrow)*40 + quad*8];
    #pragma unroll
    for (int nt = 0; nt < 4; nt++){
      s16x8 b = *(const s16x8*)&W1s[(nt*16 + lrow)*40 + quad*8];
      acc[nt] = __builtin_amdgcn_mfma_f32_16x16x32_bf16(a, b, acc[nt], 0, 0, 0);
    }
  }
  #pragma unroll
  for (int nt = 0; nt < 4; nt++){
    int n = nt*16 + lrow;
    #pragma unroll
    for (int r = 0; r < 4; r++){
      float v = acc[nt][r] + bsh[n];
      v = v > 0.f ? v : 0.01f*v;
      hs[(wid*16 + quad*4 + r)*72 + n] = bf16r(v);
    }
  }
  __syncthreads();

  #pragma unroll
  for (int t = 0; t < 4; t++) acc[t] = (f32x4){0.f,0.f,0.f,0.f};
  #pragma unroll
  for (int ks = 0; ks < 2; ks++){
    s16x8 a = *(const s16x8*)&hs[(wid*16 + lrow)*72 + ks*32 + quad*8];
    #pragma unroll
    for (int nt = 0; nt < 4; nt++){
      s16x8 b = *(const s16x8*)&W2s[(nt*16 + lrow)*72 + ks*32 + quad*8];
      acc[nt] = __builtin_amdgcn_mfma_f32_16x16x32_bf16(a, b, acc[nt], 0, 0, 0);
    }
  }
  __syncthreads();
  #pragma unroll
  for (int nt = 0; nt < 4; nt++){
    int n = nt*16 + lrow;
    #pragma unroll
    for (int r = 0; r < 4; r++){
      float v = acc[nt][r] + bsh[64 + n];
      v = v > 0.f ? v : 0.01f*v;
      hs[(wid*16 + quad*4 + r)*72 + n] = bf16r(v);
    }
  }
  __syncthreads();

  #pragma unroll
  for (int t = 0; t < 4; t++) acc[t] = (f32x4){0.f,0.f,0.f,0.f};
  #pragma unroll
  for (int ks = 0; ks < 2; ks++){
    s16x8 a = *(const s16x8*)&hs[(wid*16 + lrow)*72 + ks*32 + quad*8];
    #pragma unroll
    for (int nt = 0; nt < 4; nt++){
      s16x8 b = *(const s16x8*)&W3s[(nt*16 + lrow)*72 + ks*32 + quad*8];
      acc[nt] = __builtin_amdgcn_mfma_f32_16x16x32_bf16(a, b, acc[nt], 0, 0, 0);
    }
  }
  #pragma unroll
  for (int nt = 0; nt < 4; nt++){
    int n = nt*16 + lrow;
    #pragma unroll
    for (int r = 0; r < 4; r++){
      int m = m0 + wid*16 + quad*4 + r;
      if (m < M){
        int orow = perm ? perm[m] : m;
        float v = acc[nt][r] + bsh[128 + n];
        if (outb) outb[(size_t)orow*64 + n] = bf16r(v);
        else      out [(size_t)orow*64 + n] = v;
      }
    }
  }
}

// ---------- build augmented edge list ----------
__global__ void build_edges_k(const int* __restrict__ ei, const int* __restrict__ batch,
                              int* __restrict__ srcA, int* __restrict__ dstA){
  int idx = blockIdx.x*256 + threadIdx.x;
  if (idx >= EAUG) return;
  int s, d;
  if (idx < NE)          { s = ei[idx];              d = ei[NE+idx]; }
  else if (idx < NE+NN)  { int i = idx-NE;           s = i;            d = batch[i]+NN; }
  else if (idx < NE2)    { int i = idx-(NE+NN);      s = batch[i]+NN;  d = i; }
  else                   { int i = idx-NE2;          s = i;            d = i; }
  srcA[idx]=s; dstA[idx]=d;
}

// ---------- CSR build ----------
__global__ void count_k(const int* __restrict__ dstA, int* __restrict__ cnt){
  int e = blockIdx.x*256 + threadIdx.x;
  if (e < EAUG) atomicAdd(&cnt[dstA[e]], 1);
}

__global__ void scan_k(const int* __restrict__ cnt, int* __restrict__ rowptr){
  __shared__ int part[1024];
  int tid = threadIdx.x;
  const int per = (NAUG + 1023) / 1024;
  int base = tid * per;
  int s = 0;
  for (int i=0;i<per;i++){ int idx=base+i; if (idx<NAUG) s += cnt[idx]; }
  part[tid] = s;
  __syncthreads();
  for (int off=1; off<1024; off<<=1){
    int v = (tid>=off) ? part[tid-off] : 0;
    __syncthreads();
    part[tid] += v;
    __syncthreads();
  }
  int run = (tid==0) ? 0 : part[tid-1];
  for (int i=0;i<per;i++){
    int idx=base+i;
    if (idx<NAUG){ rowptr[idx]=run; run += cnt[idx]; }
  }
  if (tid==0) rowptr[NAUG] = EAUG;
}

__global__ void scatter_k(const int* __restrict__ srcA, const int* __restrict__ dstA,
                          const int* __restrict__ rowptr, int* __restrict__ cursor,
                          int* __restrict__ esrc, int* __restrict__ epos,
                          int* __restrict__ pdst){
  int e = blockIdx.x*256 + threadIdx.x;
  if (e >= EAUG) return;
  int d = dstA[e];
  int pos = rowptr[d] + atomicAdd(&cursor[d], 1);
  esrc[pos] = srcA[e];
  pdst[pos] = d;
  epos[e]   = pos;
}

// ---------- one-hot padding rows of aug (CSR-permuted, bf16) ----------
__global__ void set_ep_k(const int* __restrict__ epos, unsigned short* __restrict__ aug_b){
  int idx = blockIdx.x*256 + threadIdx.x;
  if (idx >= 2*NN*DD) return;
  int i = idx >> 6, c = idx & 63;
  aug_b[(size_t)epos[NE + i]*DD + c] = (c==0) ? (unsigned short)0x3F80 : (unsigned short)0;
}

// ---------- loop_attr: branch-free stream over CSR range, skip self-loop ----------
__launch_bounds__(256)
__global__ void loopmean_k(const int* __restrict__ rowptr, const int* __restrict__ epos,
                           unsigned short* __restrict__ aug_b){
  int tid = threadIdx.x;
  int d = blockIdx.x*16 + (tid>>4);
  if (d >= NAUG) return;
  int t4 = (tid & 15)*4;
  int beg = rowptr[d], end = rowptr[d+1];
  int sp = epos[NE2 + d];                  // self-loop slot (excluded)
  float4 s = make_float4(0.f,0.f,0.f,0.f);
  for (int p=beg; p<end; p++){
    float4 a = b2f4(*(const ushort4*)(aug_b + (size_t)p*DD + t4));
    float w = (p == sp) ? 0.f : 1.f;
    s.x += w*a.x; s.y += w*a.y; s.z += w*a.z; s.w += w*a.w;
  }
  int n = end - beg - 1;
  float cv = (n < 1) ? 1.f : (float)n;
  *(ushort4*)(aug_b + (size_t)sp*DD + t4) = f2b4(f4s(s, 1.f/cv));
}

// =====================================================================
// Per-graph CSR message aggregation: 2 blocks/graph, o + local-src in LDS
// =====================================================================
__launch_bounds__(512)
__global__ void msg_graph_k(const float* __restrict__ o, const unsigned short* __restrict__ aug_b,
                            const int* __restrict__ rowptr,
                            const int* __restrict__ esrc, float* __restrict__ aggsum){
  __shared__ __align__(16) float OS[101*72];
  __shared__ unsigned char EL[3072];
  const int g = blockIdx.x >> 1, half = blockIdx.x & 1;
  const int tid = threadIdx.x;
  for (int i = tid; i < 101*16; i += 512){
    int ln = i >> 4, c4 = (i & 15)*4;
    int row = (ln < 100) ? g*100 + ln : NN + g;
    *(float4*)&OS[ln*72 + c4] = *(const float4*)(o + (size_t)row*DD + c4);
  }
  const int baseA = rowptr[g*100];
  const int lenA  = rowptr[g*100 + 100] - baseA;
  const int baseB = rowptr[NN + g];
  const int lenB  = rowptr[NN + g + 1] - baseB;
  const bool useL = (lenA + lenB) <= 3072;
  if (useL){
    for (int i = tid; i < lenA; i += 512){
      int s = esrc[baseA + i];
      EL[i] = (unsigned char)((s >= NN) ? 100 : (s - g*100));
    }
    for (int i = tid; i < lenB; i += 512){
      int s = esrc[baseB + i];
      EL[lenA + i] = (unsigned char)((s >= NN) ? 100 : (s - g*100));
    }
  }
  __syncthreads();
  const int gr = tid >> 4, t4 = (tid & 15)*4;
  const int ld0 = half ? 51 : 0, ld1 = half ? 101 : 51;
  for (int ld = ld0 + gr; ld < ld1; ld += 32){
    int d, pbeg, pend, eofs;
    if (ld < 100){ d = g*100 + ld; pbeg = rowptr[d]; pend = rowptr[d+1]; eofs = -baseA; }
    else         { d = NN + g;     pbeg = baseB;     pend = baseB + lenB; eofs = lenA - baseB; }
    float4 acc = make_float4(0.f,0.f,0.f,0.f);
    for (int p = pbeg; p < pend; p++){
      int ls;
      if (useL) ls = EL[p + eofs];
      else { int s = esrc[p]; ls = (s >= NN) ? 100 : (s - g*100); }
      float4 ov = *(const float4*)&OS[ls*72 + t4];
      float4 ae = b2f4(*(const ushort4*)(aug_b + (size_t)p*DD + t4));
      acc.x += fmaxf(ov.x+ae.x, 0.f) + 1e-7f;
      acc.y += fmaxf(ov.y+ae.y, 0.f) + 1e-7f;
      acc.z += fmaxf(ov.z+ae.z, 0.f) + 1e-7f;
      acc.w += fmaxf(ov.w+ae.w, 0.f) + 1e-7f;
    }
    *(float4*)(aggsum + (size_t)d*DD + t4) = acc;
  }
}

__global__ void copy_o_xin_k(const float* __restrict__ o, float* __restrict__ xin){
  int idx = blockIdx.x*256 + threadIdx.x;
  if (idx >= NAUG*DD) return;
  int n = idx >> 6, c = idx & 63;
  xin[(size_t)n*HC + c] = o[idx];
}

// =====================================================================
// Edge-parallel logits: lg[p] = 0.125*(q[d]·k[s] + qe[d]·ae[p]) per head
// =====================================================================
__launch_bounds__(512)
__global__ void scoredot_k(const float* __restrict__ qkvs,
                           const unsigned short* __restrict__ aug_b,
                           const int* __restrict__ pdst, const int* __restrict__ esrc,
                           float2* __restrict__ lg){
  int p = blockIdx.x*32 + (threadIdx.x >> 4);
  if (p >= EAUG) return;
  int t4 = (threadIdx.x & 15)*4;
  int d = pdst[p], s = esrc[p];
  const float* qr = qkvs + (size_t)d*QS;
  const float* kr = qkvs + (size_t)s*QS + 128;
  float4 q0  = *(const float4*)(qr + t4);
  float4 q1  = *(const float4*)(qr + 64 + t4);
  float4 qe0 = *(const float4*)(qr + 512 + t4);
  float4 qe1 = *(const float4*)(qr + 576 + t4);
  float4 k0  = *(const float4*)(kr + t4);
  float4 k1  = *(const float4*)(kr + 64 + t4);
  float4 ae  = b2f4(*(const ushort4*)(aug_b + (size_t)p*DD + t4));
  float p0 = d4(q0,k0) + d4(qe0,ae);
  float p1 = d4(q1,k1) + d4(qe1,ae);
  p0 += __shfl_xor(p0,8); p0 += __shfl_xor(p0,4); p0 += __shfl_xor(p0,2); p0 += __shfl_xor(p0,1);
  p1 += __shfl_xor(p1,8); p1 += __shfl_xor(p1,4); p1 += __shfl_xor(p1,2); p1 += __shfl_xor(p1,1);
  if ((threadIdx.x & 15) == 0) lg[p] = make_float2(p0*0.125f, p1*0.125f);
}

// =====================================================================
// Attention-lite: per half-graph, V in LDS. TWO-PASS per dst:
// pass1 max over logits (restores softmax stability), pass2 accumulate
// exp(lg-m)*V (no serial rescale chain). Emits per-dst m and 1/(l+eps).
// =====================================================================
__launch_bounds__(512)
__global__ void attn_lite_k(const float* __restrict__ qkvs, const float2* __restrict__ lg,
                            const int* __restrict__ rowptr, const int* __restrict__ esrc,
                            float* __restrict__ t1, float2* __restrict__ m2,
                            float2* __restrict__ linv2){
  __shared__ __align__(16) unsigned short VS[101*128];   // 25.9 KB
  __shared__ unsigned char EL[3072];
  const int g = blockIdx.x >> 1, half = blockIdx.x & 1;
  const int tid = threadIdx.x;
  for (int i = tid; i < 101*32; i += 512){
    int ln = i >> 5, c4 = (i & 31)*4;
    int row = (ln < 100) ? g*100 + ln : NN + g;
    float4 v = *(const float4*)(qkvs + (size_t)row*QS + 256 + c4);
    *(ushort4*)&VS[ln*128 + c4] = f2b4(v);
  }
  const int baseA = rowptr[g*100];
  const int lenA  = rowptr[g*100 + 100] - baseA;
  const int baseB = rowptr[NN + g];
  const int lenB  = rowptr[NN + g + 1] - baseB;
  const bool useL = (lenA + lenB) <= 3072;
  if (useL){
    for (int i = tid; i < lenA; i += 512){
      int s = esrc[baseA + i];
      EL[i] = (unsigned char)((s >= NN) ? 100 : (s - g*100));
    }
    for (int i = tid; i < lenB; i += 512){
      int s = esrc[baseB + i];
      EL[lenA + i] = (unsigned char)((s >= NN) ? 100 : (s - g*100));
    }
  }
  __syncthreads();
  const int gr = tid >> 4, t4 = (tid & 15)*4;
  const int ld0 = half ? 51 : 0, ld1 = half ? 101 : 51;
  for (int ld = ld0 + gr; ld < ld1; ld += 32){
    int d, pbeg, pend, eofs;
    if (ld < 100){ d = g*100 + ld; pbeg = rowptr[d]; pend = rowptr[d+1]; eofs = -baseA; }
    else         { d = NN + g;     pbeg = baseB;     pend = baseB + lenB; eofs = lenA - baseB; }
    // pass 1: segment max
    float m0 = -1e30f, m1 = -1e30f;
    for (int p = pbeg; p < pend; p++){
      float2 lv = lg[p];
      m0 = fmaxf(m0, lv.x); m1 = fmaxf(m1, lv.y);
    }
    // pass 2: accumulate exp(lg - m) * V
    float l0 = 0.f, l1 = 0.f;
    float4 a0 = make_float4(0.f,0.f,0.f,0.f), a1 = a0;
    for (int p = pbeg; p < pend; p++){
      float2 lv = lg[p];
      int ls;
      if (useL) ls = EL[p + eofs];
      else { int s = esrc[p]; ls = (s >= NN) ? 100 : (s - g*100); }
      const unsigned short* vr = &VS[ls*128];
      float4 v0 = b2f4(*(const ushort4*)(vr + t4));
      float4 v1 = b2f4(*(const ushort4*)(vr + 64 + t4));
      float e0 = __expf(lv.x - m0);
      float e1 = __expf(lv.y - m1);
      l0 += e0; a0 = f4a(a0, v0, e0);
      l1 += e1; a1 = f4a(a1, v1, e1);
    }
    float i0 = 1.f/(l0 + 1e-16f), i1 = 1.f/(l1 + 1e-16f);
    *(float4*)(t1 + (size_t)d*HC + t4)      = f4s(a0, i0);
    *(float4*)(t1 + (size_t)d*HC + 64 + t4) = f4s(a1, i1);
    if ((tid & 15) == 0){
      m2[d]    = make_float2(m0, m1);
      linv2[d] = make_float2(i0, i1);
    }
  }
}

// =====================================================================
// wsum: wbuf[d] = sum_p exp(lg[p]-m[d])*linv[d] * ae[p]  (CSR groups)
// =====================================================================
__launch_bounds__(256)
__global__ void wsum_k(const unsigned short* __restrict__ aug_b, const float2* __restrict__ lg,
                       const float2* __restrict__ m2, const float2* __restrict__ linv2,
                       const int* __restrict__ rowptr, float* __restrict__ wbuf){
  int tid = threadIdx.x;
  int d = blockIdx.x*16 + (tid>>4);
  if (d >= NAUG) return;
  int t4 = (tid & 15)*4;
  float2 m = m2[d];
  float2 li = linv2[d];
  float4 w0 = make_float4(0.f,0.f,0.f,0.f), w1 = w0;
  int beg = rowptr[d], end = rowptr[d+1];
  for (int p = beg; p < end; p++){
    float2 lv = lg[p];
    float4 ae = b2f4(*(const ushort4*)(aug_b + (size_t)p*DD + t4));
    float a0 = __expf(lv.x - m.x) * li.x;
    float a1 = __expf(lv.y - m.y) * li.y;
    w0 = f4a(w0, ae, a0);
    w1 = f4a(w1, ae, a1);
  }
  *(float4*)(wbuf + (size_t)d*HC + t4)      = w0;
  *(float4*)(wbuf + (size_t)d*HC + 64 + t4) = w1;
}

// ---------- per-graph layernorm (optionally mirrors o into xin) ----------
__global__ void ln_k(const float* __restrict__ y, float* __restrict__ o,
                     float* __restrict__ xin){
  int g = blockIdx.x, tid = threadIdx.x;
  float sum=0.f, ss=0.f;
  for (int i=tid; i<101*64; i+=256){
    int nd=i>>6, c=i&63;
    int row = (nd<100) ? g*100+nd : NN+g;
    float v = y[(size_t)row*DD + c];
    sum += v; ss += v*v;
  }
  #pragma unroll
  for (int off=32; off; off>>=1){ sum += __shfl_xor(sum, off); ss += __shfl_xor(ss, off); }
  __shared__ float s1[4], s2[4];
  if ((tid&63)==0){ s1[tid>>6]=sum; s2[tid>>6]=ss; }
  __syncthreads();
  sum = s1[0]+s1[1]+s1[2]+s1[3];
  ss  = s2[0]+s2[1]+s2[2]+s2[3];
  const float inv = 1.f/6464.f;
  float mean = sum*inv;
  float var  = ss*inv - mean*mean;
  float rstd = rsqrtf(var + 1e-5f);
  for (int i=tid; i<101*64; i+=256){
    int nd=i>>6, c=i&63;
    int row = (nd<100) ? g*100+nd : NN+g;
    float v = (y[(size_t)row*DD + c] - mean)*rstd;
    o[(size_t)row*DD + c] = v;
    if (xin) xin[(size_t)row*HC + c] = v;
  }
}

__global__ void copy_c_o_k(const float* __restrict__ c_emb, float* __restrict__ o){
  int idx = blockIdx.x*256 + threadIdx.x;
  if (idx >= NG*DD) return;
  o[(size_t)NN*DD + idx] = c_emb[idx];
}

// ---------- final outputs ----------
__global__ void glob_k(const float* __restrict__ o, const float* __restrict__ c_emb,
                       float* __restrict__ gout){
  int g = blockIdx.x, c = threadIdx.x;
  float acc = 0.f;
  for (int t=0;t<100;t++) acc += o[(size_t)(g*100+t)*DD + c];
  gout[(size_t)g*192 + c]       = acc / 100.f;
  gout[(size_t)g*192 + 64 + c]  = o[(size_t)(NN+g)*DD + c];
  gout[(size_t)g*192 + 128 + c] = c_emb[(size_t)g*DD + c];
}
__global__ void ofinal_k(const float* __restrict__ o, const float* __restrict__ c_emb,
                         const int* __restrict__ batch, float* __restrict__ out){
  int idx = blockIdx.x*256 + threadIdx.x;
  if (idx >= NN*HC) return;
  int n = idx>>7, j = idx&127;
  out[idx] = (j<64) ? o[(size_t)n*DD + j] : c_emb[(size_t)batch[n]*DD + (j-64)];
}

static inline int cdiv(int a, int b){ return (a+b-1)/b; }

static inline void gemm_mfma(int N, const float* A, const float* A2, int M, int K, int lda,
                             const unsigned short* Wt, const float* bias, int act,
                             const float* res, const float* res2, int rstride,
                             float* out, int ostride, hipStream_t st){
  int KC = (K > 128) ? 128 : K;
  int KPc = KC + 8;
  size_t sh = (size_t)(N*KPc + 64*KPc) * 2;
  int grid = cdiv(M, 64);
  if (N == 64)
    gemm_mfma_k<64><<<grid,256,sh,st>>>(A,A2,M,K,lda,Wt,bias,act,res,res2,rstride,out,ostride);
  else if (N == 128)
    gemm_mfma_k<128><<<grid,256,sh,st>>>(A,A2,M,K,lda,Wt,bias,act,res,res2,rstride,out,ostride);
  else
    gemm_mfma_k<256><<<grid,256,sh,st>>>(A,A2,M,K,lda,Wt,bias,act,res,res2,rstride,out,ostride);
}

extern "C" void kernel_launch(void* const* d_in, const int* in_sizes, int n_in,
                              void* d_out, int out_size, void* d_ws, size_t ws_size,
                              hipStream_t stream){
  (void)in_sizes; (void)n_in; (void)out_size;
  const float* x         = (const float*)d_in[0];
  const float* edge_attr = (const float*)d_in[1];
  const float* cond      = (const float*)d_in[2];
  const int*   edge_index= (const int*)  d_in[3];
  const int*   batch     = (const int*)  d_in[4];
  const float* xW1=(const float*)d_in[5],  *xb1=(const float*)d_in[6],
             * xW2=(const float*)d_in[7],  *xb2=(const float*)d_in[8],
             * xW3=(const float*)d_in[9],  *xb3=(const float*)d_in[10];
  const float* eW1=(const float*)d_in[11], *eb1=(const float*)d_in[12],
             * eW2=(const float*)d_in[13], *eb2=(const float*)d_in[14],
             * eW3=(const float*)d_in[15], *eb3=(const float*)d_in[16];
  const float* cW1=(const float*)d_in[17], *cb1=(const float*)d_in[18],
             * cW2=(const float*)d_in[19], *cb2=(const float*)d_in[20],
             * cW3=(const float*)d_in[21], *cb3=(const float*)d_in[22];
  const float* gen_W=(const float*)d_in[23];
  const float* trWq=(const float*)d_in[24], *trbq=(const float*)d_in[25];
  const float* trWk=(const float*)d_in[26], *trbk=(const float*)d_in[27];
  const float* trWv=(const float*)d_in[28], *trbv=(const float*)d_in[29];
  const float* trWe=(const float*)d_in[30];
  const float* trWs=(const float*)d_in[31], *trbs=(const float*)d_in[32];
  const float* linW=(const float*)d_in[33], *linb=(const float*)d_in[34];
  const float* ffW1=(const float*)d_in[35], *ffb1=(const float*)d_in[36];
  const float* ffW2=(const float*)d_in[37], *ffb2=(const float*)d_in[38];
  float* out = (float*)d_out;

  // ---- workspace carve-up (floats) ----
  float* ws = (float*)d_ws;
  size_t off = 0;
  auto alloc = [&](size_t n)->float*{ float* p = ws + off; off += (n + 63) & ~(size_t)63; return p; };
  int*      srcA  = (int*)alloc(EAUG);
  int*      dstA  = (int*)alloc(EAUG);
  int*      cnt   = (int*)alloc(NAUG);
  int*      rowptr= (int*)alloc(NAUG+1);
  int*      cursor= (int*)alloc(NAUG);
  int*      esrc  = (int*)alloc(EAUG);
  int*      epos  = (int*)alloc(EAUG);
  int*      pdst  = (int*)alloc(EAUG);
  unsigned short* aug_b = (unsigned short*)alloc((size_t)EAUG*DD/2);  // bf16 CSR-permuted
  float*    o     = alloc((size_t)NAUG*DD);
  float*    c_emb = alloc((size_t)NG*DD);
  float*    ybuf  = alloc((size_t)NAUG*DD);
  float*    aggsum= alloc((size_t)NAUG*DD);
  float*    xin   = alloc((size_t)NAUG*HC);
  float*    xqkvs = alloc((size_t)NAUG*QS);
  float*    toutb = alloc((size_t)NAUG*HC);
  float*    t1    = alloc((size_t)NAUG*HC);
  float*    wbuf  = alloc((size_t)NAUG*HC);
  float*    ffh   = alloc((size_t)NAUG*256);
  float2*   lgb   = (float2*)alloc((size_t)EAUG*2);
  float2*   m2v   = (float2*)alloc((size_t)NAUG*2);
  float2*   li2v  = (float2*)alloc((size_t)NAUG*2);
  unsigned short* warena = (unsigned short*)alloc(210432);   // bf16 weights (39 jobs)
  unsigned short* qweb   = (unsigned short*)alloc(3*128*136/2 + 64);
  float*    bqeb  = alloc(3*128);
  if (off*sizeof(float) > ws_size) return;

  const unsigned short* wptr[39];
  int wblk = 0;
  { size_t woff = 0;
    for (int j = 0; j < 39; j++){
      wptr[j] = warena + woff;
      int e = WTAB_H[j][3]*WTAB_H[j][4];
      woff += (size_t)e;
      wblk += cdiv(e, 256);
    } }

  // ---- weight conversion + combined qe weight ----
  WPtrs wp;
  wp.p[0]=trWq; wp.p[1]=trWk; wp.p[2]=trWv; wp.p[3]=trWs; wp.p[4]=gen_W;
  wp.p[5]=linW; wp.p[6]=ffW1; wp.p[7]=ffW2; wp.p[8]=trWe;
  wp.p[9]=xW1; wp.p[10]=xW2; wp.p[11]=xW3;
  wp.p[12]=eW1; wp.p[13]=eW2; wp.p[14]=eW3;
  wp.p[15]=cW1; wp.p[16]=cW2; wp.p[17]=cW3;
  wconv_all_k<<<wblk,256,0,stream>>>(wp, warena);
  qecomb_k<<<dim3(128,3),128,0,stream>>>(trWq, trbq, trWe, qweb, bqeb);

  // ---- setup: edges + CSR (+ epos/pdst) ----
  build_edges_k<<<cdiv(EAUG,256),256,0,stream>>>(edge_index, batch, srcA, dstA);
  hipMemsetAsync(cnt, 0, sizeof(int)*NAUG, stream);
  hipMemsetAsync(cursor, 0, sizeof(int)*NAUG, stream);
  count_k<<<cdiv(EAUG,256),256,0,stream>>>(dstA, cnt);
  scan_k<<<1,1024,0,stream>>>(cnt, rowptr);
  scatter_k<<<cdiv(EAUG,256),256,0,stream>>>(srcA, dstA, rowptr, cursor, esrc, epos, pdst);

  // ---- input MLPs (edge MLP -> bf16 CSR-permuted) + pads / loop-attr ----
  mlp3_mfma_k<<<cdiv(NN,64),256,0,stream>>>(x,        NN, 32, wptr[30],wptr[31],wptr[32], xb1,xb2,xb3, nullptr, o,     nullptr);
  mlp3_mfma_k<<<cdiv(NG,64),256,0,stream>>>(cond,     NG, 32, wptr[36],wptr[37],wptr[38], cb1,cb2,cb3, nullptr, c_emb, nullptr);
  mlp3_mfma_k<<<cdiv(NE,64),256,0,stream>>>(edge_attr,NE, 16, wptr[33],wptr[34],wptr[35], eb1,eb2,eb3, epos,    nullptr, aug_b);
  set_ep_k<<<cdiv(2*NN*DD,256),256,0,stream>>>(epos, aug_b);
  loopmean_k<<<cdiv(NAUG,16),256,0,stream>>>(rowptr, epos, aug_b);
  copy_c_o_k<<<cdiv(NG*DD,256),256,0,stream>>>(c_emb, o);
  copy_o_xin_k<<<cdiv(NAUG*DD,256),256,0,stream>>>(o, xin);

  // ---- layers ----
  for (int L=0; L<3; L++){
    const float* lb_i = linb + (size_t)L*DD;
    const float* f1b  = ffb1 + (size_t)L*256;
    const float* f2b  = ffb2 + (size_t)L*DD;
    const unsigned short* genT = wptr[12+L], *linT = wptr[15+L], *ff1T = wptr[18+L], *ff2T = wptr[21+L];
    PW5 pw5;
    pw5.w[0]=wptr[0+L]; pw5.w[1]=wptr[3+L]; pw5.w[2]=wptr[6+L]; pw5.w[3]=wptr[9+L];
    pw5.w[4]=qweb + (size_t)L*128*136;
    pw5.b[0]=trbq+(size_t)L*HC; pw5.b[1]=trbk+(size_t)L*HC;
    pw5.b[2]=trbv+(size_t)L*HC; pw5.b[3]=trbs+(size_t)L*HC;
    pw5.b[4]=bqeb + (size_t)L*128;
    PW2 pwT; pwT.w[0]=wptr[24+2*L]; pwT.w[1]=wptr[25+2*L];

    msg_graph_k<<<2*NG,512,0,stream>>>(o, aug_b, rowptr, esrc, aggsum);
    gemm_mfma( 64, aggsum, o, NAUG, 64, 64, genT, nullptr, 0, nullptr, nullptr, 0, xin+64, HC, stream);
    qkvs5_k<<<dim3(cdiv(NAUG,64),5),256,0,stream>>>(xin, NAUG, pw5, xqkvs);
    scoredot_k<<<cdiv(EAUG,32),512,0,stream>>>(xqkvs, aug_b, pdst, esrc, lgb);
    attn_lite_k<<<2*NG,512,0,stream>>>(xqkvs, lgb, rowptr, esrc, t1, m2v, li2v);
    wsum_k<<<cdiv(NAUG,16),256,0,stream>>>(aug_b, lgb, m2v, li2v, rowptr, wbuf);
    tout2_k<<<dim3(cdiv(NAUG,64),2),256,0,stream>>>(wbuf, NAUG, pwT, t1, xqkvs, toutb);
    gemm_mfma( 64, toutb, nullptr, NAUG, 128, 128, linT, lb_i, 0, o, nullptr, DD, ybuf, DD, stream);
    ln_k<<<NG,256,0,stream>>>(ybuf, o, nullptr);
    gemm_mfma(256, o,   nullptr, NAUG,  64,  64, ff1T, f1b, 1, nullptr, nullptr, 0, ffh, 256, stream);
    gemm_mfma( 64, ffh, nullptr, NAUG, 256, 256, ff2T, f2b, 0, o, nullptr, DD, ybuf, DD, stream);
    ln_k<<<NG,256,0,stream>>>(ybuf, o, xin);
  }

  // ---- outputs ----
  glob_k<<<NG,64,0,stream>>>(o, c_emb, out + (size_t)NN*HC);
  ofinal_k<<<cdiv(NN*HC,256),256,0,stream>>>(o, c_emb, batch, out);
}

// Round 10
// 1282.999 us; speedup vs baseline: 1.0425x; 1.0261x over previous
//
#include <hip/hip_runtime.h>
#include <cstddef>

#define NN   20000          // real nodes
#define NG   200            // graphs / virtual nodes
#define NE   320000         // original edges
#define NAUG 20200          // NN + NG
#define NE2  360000         // NE + 2*NN  (edges before self-loops)
#define EAUG 380200         // NE2 + NAUG
#define DD   64             // NUM_EMB
#define HC   128            // HEADS * NUM_EMB
#define QS   640            // xqkvs row stride: [q|k|v|xs|qe]

typedef float  f32x4 __attribute__((ext_vector_type(4)));
typedef short  s16x8 __attribute__((ext_vector_type(8)));

static __device__ __forceinline__ unsigned short bf16r(float f){
  unsigned u = __float_as_uint(f);
  u += 0x7FFFu + ((u >> 16) & 1u);
  return (unsigned short)(u >> 16);
}
static __device__ __forceinline__ float4 b2f4(ushort4 u){
  return make_float4(__uint_as_float((unsigned)u.x << 16),
                     __uint_as_float((unsigned)u.y << 16),
                     __uint_as_float((unsigned)u.z << 16),
                     __uint_as_float((unsigned)u.w << 16));
}
static __device__ __forceinline__ ushort4 f2b4(float4 v){
  ushort4 s; s.x=bf16r(v.x); s.y=bf16r(v.y); s.z=bf16r(v.z); s.w=bf16r(v.w); return s;
}
static __device__ __forceinline__ float d4(float4 a, float4 b){
  return a.x*b.x + a.y*b.y + a.z*b.z + a.w*b.w;
}
static __device__ __forceinline__ float4 f4a(float4 a, float4 b, float t){
  return make_float4(a.x + b.x*t, a.y + b.y*t, a.z + b.z*t, a.w + b.w*t);
}
static __device__ __forceinline__ float4 f4s(float4 a, float s){
  return make_float4(a.x*s, a.y*s, a.z*s, a.w*s);
}

// =====================================================================
// Weight pre-conversion: fp32 -> bf16, transposed to Bt[n][k], stride KP=K+8
// {srcIdx, mode, Ksrc, N, KP, stride, soff}; mode0 transpose, mode1 direct
// =====================================================================
#define WTAB_INIT { \
  {0,0,128,128,136,128,0},{0,0,128,128,136,128,16384},{0,0,128,128,136,128,32768}, \
  {1,0,128,128,136,128,0},{1,0,128,128,136,128,16384},{1,0,128,128,136,128,32768}, \
  {2,0,128,128,136,128,0},{2,0,128,128,136,128,16384},{2,0,128,128,136,128,32768}, \
  {3,0,128,128,136,128,0},{3,0,128,128,136,128,16384},{3,0,128,128,136,128,32768}, \
  {4,0,64,64,72,64,0},{4,0,64,64,72,64,4096},{4,0,64,64,72,64,8192}, \
  {5,0,128,64,136,64,0},{5,0,128,64,136,64,8192},{5,0,128,64,136,64,16384}, \
  {6,0,64,256,72,256,0},{6,0,64,256,72,256,16384},{6,0,64,256,72,256,32768}, \
  {7,0,256,64,264,64,0},{7,0,256,64,264,64,16384},{7,0,256,64,264,64,32768}, \
  {8,0,64,64,72,128,0},{8,0,64,64,72,128,64},{8,0,64,64,72,128,8192},{8,0,64,64,72,128,8256},{8,0,64,64,72,128,16384},{8,0,64,64,72,128,16448}, \
  {9,0,32,64,40,64,0},{10,0,64,64,72,64,0},{11,0,64,64,72,64,0}, \
  {12,0,16,64,40,64,0},{13,0,64,64,72,64,0},{14,0,64,64,72,64,0}, \
  {15,0,32,64,40,64,0},{16,0,64,64,72,64,0},{17,0,64,64,72,64,0} }

static const int WTAB_H[39][7] = WTAB_INIT;
__device__ static const int WTAB_D[39][7] = WTAB_INIT;

struct WPtrs { const float* p[18]; };

__global__ void wconv_all_k(WPtrs wp, unsigned short* __restrict__ outbase){
  int b = blockIdx.x;
  int acc = 0; unsigned ooff = 0;
  #pragma unroll 1
  for (int j = 0; j < 39; j++){
    int e  = WTAB_D[j][3] * WTAB_D[j][4];
    int nb = (e + 255) >> 8;
    if (b < acc + nb){
      int idx = (b - acc)*256 + threadIdx.x;
      if (idx < e){
        int KP = WTAB_D[j][4];
        int n = idx / KP, k = idx % KP;
        float v = 0.f;
        if (k < WTAB_D[j][2]){
          const float* s = wp.p[WTAB_D[j][0]];
          int st = WTAB_D[j][5], so = WTAB_D[j][6];
          v = (WTAB_D[j][1] == 0) ? s[(size_t)so + (size_t)k*st + n]
                                  : s[(size_t)so + (size_t)n*st + k];
        }
        outbase[ooff + idx] = bf16r(v);
      }
      return;
    }
    acc += nb; ooff += (unsigned)e;
  }
}

// =====================================================================
// Combined qe weight: Wqe[i, h*64+d] = sum_c Wq[i,h*64+c]*We[d,h*64+c]
// =====================================================================
__global__ void qecomb_k(const float* __restrict__ trWq, const float* __restrict__ trbq,
                         const float* __restrict__ trWe,
                         unsigned short* __restrict__ qweb, float* __restrict__ bqeb){
  int L = blockIdx.y;
  int n = blockIdx.x;            // h*64+d
  int i = threadIdx.x;           // 0..127
  int h = n >> 6, d = n & 63;
  const float* Wq = trWq + (size_t)L*128*128;
  const float* We = trWe + (size_t)L*64*128;
  float acc = 0.f;
  for (int c = 0; c < 64; c++)
    acc += Wq[(size_t)i*128 + h*64 + c] * We[(size_t)d*128 + h*64 + c];
  qweb[(size_t)L*128*136 + n*136 + i] = bf16r(acc);
  if (i < 8) qweb[(size_t)L*128*136 + n*136 + 128 + i] = 0;
  if (i == 0){
    const float* bq = trbq + (size_t)L*128;
    float b = 0.f;
    for (int c = 0; c < 64; c++) b += bq[h*64 + c] * We[(size_t)d*128 + h*64 + c];
    bqeb[L*128 + n] = b;
  }
}

// =====================================================================
// Generic MFMA GEMM (template N)
// =====================================================================
template<int NT>
__launch_bounds__(256)
__global__ void gemm_mfma_k(const float* __restrict__ A, const float* __restrict__ A2,
                            int M, int K, int lda,
                            const unsigned short* __restrict__ WtG,
                            const float* __restrict__ bias, int act,
                            const float* __restrict__ res, const float* __restrict__ res2,
                            int rstride, float* __restrict__ out, int ostride){
  extern __shared__ unsigned short smem[];
  const int KC  = (K > 128) ? 128 : K;
  const int KPc = KC + 8;
  const int KP  = K + 8;
  unsigned short* Wts  = smem;
  unsigned short* Asub = smem + NT*KPc;
  const int tid = threadIdx.x;
  const int wid = tid >> 6, lane = tid & 63;
  const int lrow = lane & 15, quad = lane >> 4;
  const int m0 = blockIdx.x * 64;
  f32x4 acc[NT/16];
  #pragma unroll
  for (int t = 0; t < NT/16; t++) acc[t] = (f32x4){0.f,0.f,0.f,0.f};

  for (int k0 = 0; k0 < K; k0 += KC){
    const int wv = NT*KPc/8, wrow = KPc/8;
    for (int i = tid; i < wv; i += 256){
      int n = i / wrow, c8 = i % wrow;
      *(uint4*)&Wts[n*KPc + c8*8] = *(const uint4*)&WtG[(size_t)n*KP + k0 + c8*8];
    }
    const int av = 64*KC/4, arow = KC/4;
    for (int i = tid; i < av; i += 256){
      int r = i / arow, c4i = i % arow;
      int m = m0 + r, k = k0 + c4i*4;
      float4 v = make_float4(0.f,0.f,0.f,0.f);
      if (m < M){
        v = *(const float4*)(A + (size_t)m*lda + k);
        if (A2){ float4 w = *(const float4*)(A2 + (size_t)m*lda + k);
                 v.x += w.x; v.y += w.y; v.z += w.z; v.w += w.w; }
      }
      *(ushort4*)&Asub[r*KPc + c4i*4] = f2b4(v);
    }
    __syncthreads();
    const int ksteps = KC >> 5;
    for (int ks = 0; ks < ksteps; ks++){
      s16x8 a = *(const s16x8*)&Asub[(wid*16 + lrow)*KPc + ks*32 + quad*8];
      #pragma unroll
      for (int nt = 0; nt < NT/16; nt++){
        s16x8 b = *(const s16x8*)&Wts[(nt*16 + lrow)*KPc + ks*32 + quad*8];
        acc[nt] = __builtin_amdgcn_mfma_f32_16x16x32_bf16(a, b, acc[nt], 0, 0, 0);
      }
    }
    __syncthreads();
  }

  const int mb = m0 + wid*16 + quad*4;
  #pragma unroll
  for (int nt = 0; nt < NT/16; nt++){
    int n = nt*16 + lrow;
    #pragma unroll
    for (int r = 0; r < 4; r++){
      int m = mb + r;
      if (m < M){
        float v = acc[nt][r];
        if (bias) v += bias[n];
        if (act)  v = v > 0.f ? v : 0.01f*v;
        if (res)  v += res [(size_t)m*rstride + n];
        if (res2) v += res2[(size_t)m*rstride + n];
        out[(size_t)m*ostride + n] = v;
      }
    }
  }
}

// =====================================================================
// Batched QKVS+QE GEMM: grid.y in [0,5); out[m, y*128 + n], ostride QS
// =====================================================================
struct PW5 { const unsigned short* w[5]; const float* b[5]; };

__launch_bounds__(256)
__global__ void qkvs5_k(const float* __restrict__ A, int M, PW5 pw,
                        float* __restrict__ out){
  __shared__ __align__(16) unsigned short Wts[128*136];
  __shared__ __align__(16) unsigned short Asub[64*136];
  const unsigned short* WtG = pw.w[blockIdx.y];
  const float* bias = pw.b[blockIdx.y];
  const int tid = threadIdx.x;
  const int wid = tid >> 6, lane = tid & 63;
  const int lrow = lane & 15, quad = lane >> 4;
  const int m0 = blockIdx.x * 64;
  for (int i = tid; i < 128*17; i += 256){
    int n = i/17, c8 = i%17;
    *(uint4*)&Wts[n*136 + c8*8] = *(const uint4*)&WtG[(size_t)n*136 + c8*8];
  }
  for (int i = tid; i < 64*32; i += 256){
    int r = i >> 5, c4 = (i & 31)*4;
    int m = m0 + r;
    float4 v = make_float4(0.f,0.f,0.f,0.f);
    if (m < M) v = *(const float4*)(A + (size_t)m*128 + c4);
    *(ushort4*)&Asub[r*136 + c4] = f2b4(v);
  }
  __syncthreads();
  f32x4 acc[8];
  #pragma unroll
  for (int t=0;t<8;t++) acc[t] = (f32x4){0.f,0.f,0.f,0.f};
  #pragma unroll
  for (int ks = 0; ks < 4; ks++){
    s16x8 a = *(const s16x8*)&Asub[(wid*16 + lrow)*136 + ks*32 + quad*8];
    #pragma unroll
    for (int nt = 0; nt < 8; nt++){
      s16x8 b = *(const s16x8*)&Wts[(nt*16 + lrow)*136 + ks*32 + quad*8];
      acc[nt] = __builtin_amdgcn_mfma_f32_16x16x32_bf16(a, b, acc[nt], 0, 0, 0);
    }
  }
  const int mb = m0 + wid*16 + quad*4;
  const int yoff = blockIdx.y*128;
  #pragma unroll
  for (int nt = 0; nt < 8; nt++){
    int n = nt*16 + lrow;
    #pragma unroll
    for (int r = 0; r < 4; r++){
      int m = mb + r;
      if (m < M) out[(size_t)m*QS + yoff + n] = acc[nt][r] + bias[n];
    }
  }
}

// =====================================================================
// Batched per-head 64x64 GEMM (tout) — grid.y = head
// =====================================================================
struct PW2 { const unsigned short* w[2]; };

__launch_bounds__(256)
__global__ void tout2_k(const float* __restrict__ wv, int M, PW2 pw,
                        const float* __restrict__ t1, const float* __restrict__ qkvs,
                        float* __restrict__ tout){
  __shared__ __align__(16) unsigned short Wts[64*72];
  __shared__ __align__(16) unsigned short Asub[64*72];
  const unsigned short* WtG = pw.w[blockIdx.y];
  const int tid = threadIdx.x;
  const int wid = tid >> 6, lane = tid & 63;
  const int lrow = lane & 15, quad = lane >> 4;
  const int m0 = blockIdx.x * 64;
  const int yoff = blockIdx.y * 64;
  for (int i = tid; i < 64*9; i += 256){
    int n = i/9, c8 = i%9;
    *(uint4*)&Wts[n*72 + c8*8] = *(const uint4*)&WtG[(size_t)n*72 + c8*8];
  }
  for (int i = tid; i < 64*16; i += 256){
    int r = i >> 4, c4 = (i & 15)*4;
    int m = m0 + r;
    float4 v = make_float4(0.f,0.f,0.f,0.f);
    if (m < M) v = *(const float4*)(wv + (size_t)m*HC + yoff + c4);
    *(ushort4*)&Asub[r*72 + c4] = f2b4(v);
  }
  __syncthreads();
  f32x4 acc[4];
  #pragma unroll
  for (int t=0;t<4;t++) acc[t] = (f32x4){0.f,0.f,0.f,0.f};
  #pragma unroll
  for (int ks = 0; ks < 2; ks++){
    s16x8 a = *(const s16x8*)&Asub[(wid*16 + lrow)*72 + ks*32 + quad*8];
    #pragma unroll
    for (int nt = 0; nt < 4; nt++){
      s16x8 b = *(const s16x8*)&Wts[(nt*16 + lrow)*72 + ks*32 + quad*8];
      acc[nt] = __builtin_amdgcn_mfma_f32_16x16x32_bf16(a, b, acc[nt], 0, 0, 0);
    }
  }
  const int mb = m0 + wid*16 + quad*4;
  #pragma unroll
  for (int nt = 0; nt < 4; nt++){
    int n = nt*16 + lrow;
    #pragma unroll
    for (int r = 0; r < 4; r++){
      int m = mb + r;
      if (m < M)
        tout[(size_t)m*HC + yoff + n] = acc[nt][r]
          + t1[(size_t)m*HC + yoff + n] + qkvs[(size_t)m*QS + 384 + yoff + n];
    }
  }
}

// =====================================================================
// Fused 3-layer MLP via MFMA — wave-private tiles, single barrier.
// Each wave owns 16 rows end-to-end; inter-layer transpose via
// wave-private LDS slice (no __syncthreads in the pipeline).
// =====================================================================
__launch_bounds__(256)
__global__ void mlp3_mfma_k(const float* __restrict__ X, int M, int Din,
                            const unsigned short* __restrict__ w1t,
                            const unsigned short* __restrict__ w2t,
                            const unsigned short* __restrict__ w3t,
                            const float* __restrict__ b1, const float* __restrict__ b2,
                            const float* __restrict__ b3,
                            const int* __restrict__ perm, float* __restrict__ out,
                            unsigned short* __restrict__ outb){
  __shared__ __align__(16) unsigned short W1s[64*40], W2s[64*72], W3s[64*72];
  __shared__ __align__(16) unsigned short xs[4][16*40];
  __shared__ __align__(16) unsigned short hs[4][16*72];
  __shared__ float bsh[192];
  const int tid = threadIdx.x;
  const int wid = tid >> 6, lane = tid & 63;
  const int lrow = lane & 15, quad = lane >> 4;
  for (int i = tid; i < 320; i += 256)  *(uint4*)&W1s[i*8] = *(const uint4*)&w1t[i*8];
  for (int i = tid; i < 576; i += 256){ *(uint4*)&W2s[i*8] = *(const uint4*)&w2t[i*8];
                                        *(uint4*)&W3s[i*8] = *(const uint4*)&w3t[i*8]; }
  if (tid < 64){ bsh[tid] = b1[tid]; bsh[64+tid] = b2[tid]; bsh[128+tid] = b3[tid]; }

  // wave-private input load: wave wid loads its 16 rows (4 lanes/row, 8 floats/lane)
  const int m0 = blockIdx.x*64 + wid*16;
  {
    int r = lane >> 2, c8 = (lane & 3) * 8;       // float offset within row
    int m = m0 + r;
    float4 va = make_float4(0.f,0.f,0.f,0.f), vb = va;
    if (m < M && c8 < Din){
      va = *(const float4*)(X + (size_t)m*Din + c8);
      vb = *(const float4*)(X + (size_t)m*Din + c8 + 4);
    }
    *(ushort4*)&xs[wid][r*40 + c8]     = f2b4(va);
    *(ushort4*)&xs[wid][r*40 + c8 + 4] = f2b4(vb);
  }
  __syncthreads();   // weights + biases visible (xs is wave-private)

  f32x4 acc[4];
  // ---- layer 1 (K=32) ----
  #pragma unroll
  for (int t = 0; t < 4; t++) acc[t] = (f32x4){0.f,0.f,0.f,0.f};
  {
    s16x8 a = *(const s16x8*)&xs[wid][lrow*40 + quad*8];
    #pragma unroll
    for (int nt = 0; nt < 4; nt++){
      s16x8 b = *(const s16x8*)&W1s[(nt*16 + lrow)*40 + quad*8];
      acc[nt] = __builtin_amdgcn_mfma_f32_16x16x32_bf16(a, b, acc[nt], 0, 0, 0);
    }
  }
  #pragma unroll
  for (int nt = 0; nt < 4; nt++){
    int n = nt*16 + lrow;
    #pragma unroll
    for (int r = 0; r < 4; r++){
      float v = acc[nt][r] + bsh[n];
      v = v > 0.f ? v : 0.01f*v;
      hs[wid][(quad*4 + r)*72 + n] = bf16r(v);
    }
  }
  // ---- layer 2 (K=64) — wave-private, no barrier ----
  #pragma unroll
  for (int t = 0; t < 4; t++) acc[t] = (f32x4){0.f,0.f,0.f,0.f};
  #pragma unroll
  for (int ks = 0; ks < 2; ks++){
    s16x8 a = *(const s16x8*)&hs[wid][lrow*72 + ks*32 + quad*8];
    #pragma unroll
    for (int nt = 0; nt < 4; nt++){
      s16x8 b = *(const s16x8*)&W2s[(nt*16 + lrow)*72 + ks*32 + quad*8];
      acc[nt] = __builtin_amdgcn_mfma_f32_16x16x32_bf16(a, b, acc[nt], 0, 0, 0);
    }
  }
  #pragma unroll
  for (int nt = 0; nt < 4; nt++){
    int n = nt*16 + lrow;
    #pragma unroll
    for (int r = 0; r < 4; r++){
      float v = acc[nt][r] + bsh[64 + n];
      v = v > 0.f ? v : 0.01f*v;
      hs[wid][(quad*4 + r)*72 + n] = bf16r(v);
    }
  }
  // ---- layer 3 (K=64) ----
  #pragma unroll
  for (int t = 0; t < 4; t++) acc[t] = (f32x4){0.f,0.f,0.f,0.f};
  #pragma unroll
  for (int ks = 0; ks < 2; ks++){
    s16x8 a = *(const s16x8*)&hs[wid][lrow*72 + ks*32 + quad*8];
    #pragma unroll
    for (int nt = 0; nt < 4; nt++){
      s16x8 b = *(const s16x8*)&W3s[(nt*16 + lrow)*72 + ks*32 + quad*8];
      acc[nt] = __builtin_amdgcn_mfma_f32_16x16x32_bf16(a, b, acc[nt], 0, 0, 0);
    }
  }
  #pragma unroll
  for (int nt = 0; nt < 4; nt++){
    int n = nt*16 + lrow;
    #pragma unroll
    for (int r = 0; r < 4; r++){
      int m = m0 + quad*4 + r;
      if (m < M){
        int orow = perm ? perm[m] : m;
        float v = acc[nt][r] + bsh[128 + n];
        if (outb) outb[(size_t)orow*64 + n] = bf16r(v);
        else      out [(size_t)orow*64 + n] = v;
      }
    }
  }
}

// ---------- build augmented edge list (+degree count) ----------
__global__ void build_edges_k(const int* __restrict__ ei, const int* __restrict__ batch,
                              int* __restrict__ srcA, int* __restrict__ dstA,
                              int* __restrict__ cnt){
  int idx = blockIdx.x*256 + threadIdx.x;
  if (idx >= EAUG) return;
  int s, d;
  if (idx < NE)          { s = ei[idx];              d = ei[NE+idx]; }
  else if (idx < NE+NN)  { int i = idx-NE;           s = i;            d = batch[i]+NN; }
  else if (idx < NE2)    { int i = idx-(NE+NN);      s = batch[i]+NN;  d = i; }
  else                   { int i = idx-NE2;          s = i;            d = i; }
  srcA[idx]=s; dstA[idx]=d;
  atomicAdd(&cnt[d], 1);
}

__global__ void scan_k(const int* __restrict__ cnt, int* __restrict__ rowptr){
  __shared__ int part[1024];
  int tid = threadIdx.x;
  const int per = (NAUG + 1023) / 1024;
  int base = tid * per;
  int s = 0;
  for (int i=0;i<per;i++){ int idx=base+i; if (idx<NAUG) s += cnt[idx]; }
  part[tid] = s;
  __syncthreads();
  for (int off=1; off<1024; off<<=1){
    int v = (tid>=off) ? part[tid-off] : 0;
    __syncthreads();
    part[tid] += v;
    __syncthreads();
  }
  int run = (tid==0) ? 0 : part[tid-1];
  for (int i=0;i<per;i++){
    int idx=base+i;
    if (idx<NAUG){ rowptr[idx]=run; run += cnt[idx]; }
  }
  if (tid==0) rowptr[NAUG] = EAUG;
}

// scatter: one random 4B write (eid) + sequential epos
__global__ void scatter_k(const int* __restrict__ dstA,
                          const int* __restrict__ rowptr, int* __restrict__ cursor,
                          int* __restrict__ eid, int* __restrict__ epos){
  int e = blockIdx.x*256 + threadIdx.x;
  if (e >= EAUG) return;
  int d = dstA[e];
  int pos = rowptr[d] + atomicAdd(&cursor[d], 1);
  eid[pos] = e;
  epos[e]  = pos;
}

// esrc[p] = srcA[eid[p]]  (sequential write, random L2-warm read)
__global__ void fill_esrc_k(const int* __restrict__ eid, const int* __restrict__ srcA,
                            int* __restrict__ esrc){
  int p = blockIdx.x*256 + threadIdx.x;
  if (p < EAUG) esrc[p] = srcA[eid[p]];
}

// pdst[rowptr[d]..rowptr[d+1]) = d  (sequential range writes)
__launch_bounds__(256)
__global__ void fill_pdst_k(const int* __restrict__ rowptr, int* __restrict__ pdst){
  int d = blockIdx.x*16 + (threadIdx.x >> 4);
  if (d >= NAUG) return;
  int lane = threadIdx.x & 15;
  int beg = rowptr[d], end = rowptr[d+1];
  for (int p = beg + lane; p < end; p += 16) pdst[p] = d;
}

// ---------- one-hot padding rows of aug (CSR-permuted, bf16) ----------
__global__ void set_ep_k(const int* __restrict__ epos, unsigned short* __restrict__ aug_b){
  int idx = blockIdx.x*256 + threadIdx.x;
  if (idx >= 2*NN*DD) return;
  int i = idx >> 6, c = idx & 63;
  aug_b[(size_t)epos[NE + i]*DD + c] = (c==0) ? (unsigned short)0x3F80 : (unsigned short)0;
}

// ---------- loop_attr: branch-free stream over CSR range, skip self-loop ----------
__launch_bounds__(256)
__global__ void loopmean_k(const int* __restrict__ rowptr, const int* __restrict__ epos,
                           unsigned short* __restrict__ aug_b){
  int tid = threadIdx.x;
  int d = blockIdx.x*16 + (tid>>4);
  if (d >= NAUG) return;
  int t4 = (tid & 15)*4;
  int beg = rowptr[d], end = rowptr[d+1];
  int sp = epos[NE2 + d];
  float4 s = make_float4(0.f,0.f,0.f,0.f);
  for (int p=beg; p<end; p++){
    float4 a = b2f4(*(const ushort4*)(aug_b + (size_t)p*DD + t4));
    float w = (p == sp) ? 0.f : 1.f;
    s.x += w*a.x; s.y += w*a.y; s.z += w*a.z; s.w += w*a.w;
  }
  int n = end - beg - 1;
  float cv = (n < 1) ? 1.f : (float)n;
  *(ushort4*)(aug_b + (size_t)sp*DD + t4) = f2b4(f4s(s, 1.f/cv));
}

// =====================================================================
// Per-graph CSR message aggregation: 2 blocks/graph, o + local-src in LDS
// =====================================================================
__launch_bounds__(512)
__global__ void msg_graph_k(const float* __restrict__ o, const unsigned short* __restrict__ aug_b,
                            const int* __restrict__ rowptr,
                            const int* __restrict__ esrc, float* __restrict__ aggsum){
  __shared__ __align__(16) float OS[101*72];
  __shared__ unsigned char EL[3072];
  const int g = blockIdx.x >> 1, half = blockIdx.x & 1;
  const int tid = threadIdx.x;
  for (int i = tid; i < 101*16; i += 512){
    int ln = i >> 4, c4 = (i & 15)*4;
    int row = (ln < 100) ? g*100 + ln : NN + g;
    *(float4*)&OS[ln*72 + c4] = *(const float4*)(o + (size_t)row*DD + c4);
  }
  const int baseA = rowptr[g*100];
  const int lenA  = rowptr[g*100 + 100] - baseA;
  const int baseB = rowptr[NN + g];
  const int lenB  = rowptr[NN + g + 1] - baseB;
  const bool useL = (lenA + lenB) <= 3072;
  if (useL){
    for (int i = tid; i < lenA; i += 512){
      int s = esrc[baseA + i];
      EL[i] = (unsigned char)((s >= NN) ? 100 : (s - g*100));
    }
    for (int i = tid; i < lenB; i += 512){
      int s = esrc[baseB + i];
      EL[lenA + i] = (unsigned char)((s >= NN) ? 100 : (s - g*100));
    }
  }
  __syncthreads();
  const int gr = tid >> 4, t4 = (tid & 15)*4;
  const int ld0 = half ? 51 : 0, ld1 = half ? 101 : 51;
  for (int ld = ld0 + gr; ld < ld1; ld += 32){
    int d, pbeg, pend, eofs;
    if (ld < 100){ d = g*100 + ld; pbeg = rowptr[d]; pend = rowptr[d+1]; eofs = -baseA; }
    else         { d = NN + g;     pbeg = baseB;     pend = baseB + lenB; eofs = lenA - baseB; }
    float4 acc = make_float4(0.f,0.f,0.f,0.f);
    for (int p = pbeg; p < pend; p++){
      int ls;
      if (useL) ls = EL[p + eofs];
      else { int s = esrc[p]; ls = (s >= NN) ? 100 : (s - g*100); }
      float4 ov = *(const float4*)&OS[ls*72 + t4];
      float4 ae = b2f4(*(const ushort4*)(aug_b + (size_t)p*DD + t4));
      acc.x += fmaxf(ov.x+ae.x, 0.f) + 1e-7f;
      acc.y += fmaxf(ov.y+ae.y, 0.f) + 1e-7f;
      acc.z += fmaxf(ov.z+ae.z, 0.f) + 1e-7f;
      acc.w += fmaxf(ov.w+ae.w, 0.f) + 1e-7f;
    }
    *(float4*)(aggsum + (size_t)d*DD + t4) = acc;
  }
}

__global__ void copy_o_xin_k(const float* __restrict__ o, float* __restrict__ xin){
  int idx = blockIdx.x*256 + threadIdx.x;
  if (idx >= NAUG*DD) return;
  int n = idx >> 6, c = idx & 63;
  xin[(size_t)n*HC + c] = o[idx];
}

// =====================================================================
// Edge-parallel logits: lg[p] = 0.125*(q[d]·k[s] + qe[d]·ae[p]) per head
// =====================================================================
__launch_bounds__(512)
__global__ void scoredot_k(const float* __restrict__ qkvs,
                           const unsigned short* __restrict__ aug_b,
                           const int* __restrict__ pdst, const int* __restrict__ esrc,
                           float2* __restrict__ lg){
  int p = blockIdx.x*32 + (threadIdx.x >> 4);
  if (p >= EAUG) return;
  int t4 = (threadIdx.x & 15)*4;
  int d = pdst[p], s = esrc[p];
  const float* qr = qkvs + (size_t)d*QS;
  const float* kr = qkvs + (size_t)s*QS + 128;
  float4 q0  = *(const float4*)(qr + t4);
  float4 q1  = *(const float4*)(qr + 64 + t4);
  float4 qe0 = *(const float4*)(qr + 512 + t4);
  float4 qe1 = *(const float4*)(qr + 576 + t4);
  float4 k0  = *(const float4*)(kr + t4);
  float4 k1  = *(const float4*)(kr + 64 + t4);
  float4 ae  = b2f4(*(const ushort4*)(aug_b + (size_t)p*DD + t4));
  float p0 = d4(q0,k0) + d4(qe0,ae);
  float p1 = d4(q1,k1) + d4(qe1,ae);
  p0 += __shfl_xor(p0,8); p0 += __shfl_xor(p0,4); p0 += __shfl_xor(p0,2); p0 += __shfl_xor(p0,1);
  p1 += __shfl_xor(p1,8); p1 += __shfl_xor(p1,4); p1 += __shfl_xor(p1,2); p1 += __shfl_xor(p1,1);
  if ((threadIdx.x & 15) == 0) lg[p] = make_float2(p0*0.125f, p1*0.125f);
}

// =====================================================================
// Attention (fused t1 + wbuf): per half-graph, V in LDS. Two-pass per dst:
// pass1 segment max; pass2 accumulates exp(lg-m)*V (LDS) and exp(lg-m)*ae
// (global stream). Both outputs normalized by 1/(l+eps).
// =====================================================================
__launch_bounds__(512)
__global__ void attn_lite_k(const float* __restrict__ qkvs, const float2* __restrict__ lg,
                            const unsigned short* __restrict__ aug_b,
                            const int* __restrict__ rowptr, const int* __restrict__ esrc,
                            float* __restrict__ t1, float* __restrict__ wbuf){
  __shared__ __align__(16) unsigned short VS[101*128];
  __shared__ unsigned char EL[3072];
  const int g = blockIdx.x >> 1, half = blockIdx.x & 1;
  const int tid = threadIdx.x;
  for (int i = tid; i < 101*32; i += 512){
    int ln = i >> 5, c4 = (i & 31)*4;
    int row = (ln < 100) ? g*100 + ln : NN + g;
    float4 v = *(const float4*)(qkvs + (size_t)row*QS + 256 + c4);
    *(ushort4*)&VS[ln*128 + c4] = f2b4(v);
  }
  const int baseA = rowptr[g*100];
  const int lenA  = rowptr[g*100 + 100] - baseA;
  const int baseB = rowptr[NN + g];
  const int lenB  = rowptr[NN + g + 1] - baseB;
  const bool useL = (lenA + lenB) <= 3072;
  if (useL){
    for (int i = tid; i < lenA; i += 512){
      int s = esrc[baseA + i];
      EL[i] = (unsigned char)((s >= NN) ? 100 : (s - g*100));
    }
    for (int i = tid; i < lenB; i += 512){
      int s = esrc[baseB + i];
      EL[lenA + i] = (unsigned char)((s >= NN) ? 100 : (s - g*100));
    }
  }
  __syncthreads();
  const int gr = tid >> 4, t4 = (tid & 15)*4;
  const int ld0 = half ? 51 : 0, ld1 = half ? 101 : 51;
  for (int ld = ld0 + gr; ld < ld1; ld += 32){
    int d, pbeg, pend, eofs;
    if (ld < 100){ d = g*100 + ld; pbeg = rowptr[d]; pend = rowptr[d+1]; eofs = -baseA; }
    else         { d = NN + g;     pbeg = baseB;     pend = baseB + lenB; eofs = lenA - baseB; }
    // pass 1: segment max
    float m0 = -1e30f, m1 = -1e30f;
    for (int p = pbeg; p < pend; p++){
      float2 lv = lg[p];
      m0 = fmaxf(m0, lv.x); m1 = fmaxf(m1, lv.y);
    }
    // pass 2: accumulate exp(lg - m) * {V, ae}
    float l0 = 0.f, l1 = 0.f;
    float4 a0 = make_float4(0.f,0.f,0.f,0.f), a1 = a0, w0 = a0, w1 = a0;
    for (int p = pbeg; p < pend; p++){
      float2 lv = lg[p];
      int ls;
      if (useL) ls = EL[p + eofs];
      else { int s = esrc[p]; ls = (s >= NN) ? 100 : (s - g*100); }
      const unsigned short* vr = &VS[ls*128];
      float4 v0 = b2f4(*(const ushort4*)(vr + t4));
      float4 v1 = b2f4(*(const ushort4*)(vr + 64 + t4));
      float4 ae = b2f4(*(const ushort4*)(aug_b + (size_t)p*DD + t4));
      float e0 = __expf(lv.x - m0);
      float e1 = __expf(lv.y - m1);
      l0 += e0; a0 = f4a(a0, v0, e0); w0 = f4a(w0, ae, e0);
      l1 += e1; a1 = f4a(a1, v1, e1); w1 = f4a(w1, ae, e1);
    }
    float i0 = 1.f/(l0 + 1e-16f), i1 = 1.f/(l1 + 1e-16f);
    *(float4*)(t1   + (size_t)d*HC + t4)      = f4s(a0, i0);
    *(float4*)(t1   + (size_t)d*HC + 64 + t4) = f4s(a1, i1);
    *(float4*)(wbuf + (size_t)d*HC + t4)      = f4s(w0, i0);
    *(float4*)(wbuf + (size_t)d*HC + 64 + t4) = f4s(w1, i1);
  }
}

// ---------- per-graph layernorm (optionally mirrors o into xin) ----------
__global__ void ln_k(const float* __restrict__ y, float* __restrict__ o,
                     float* __restrict__ xin){
  int g = blockIdx.x, tid = threadIdx.x;
  float sum=0.f, ss=0.f;
  for (int i=tid; i<101*64; i+=256){
    int nd=i>>6, c=i&63;
    int row = (nd<100) ? g*100+nd : NN+g;
    float v = y[(size_t)row*DD + c];
    sum += v; ss += v*v;
  }
  #pragma unroll
  for (int off=32; off; off>>=1){ sum += __shfl_xor(sum, off); ss += __shfl_xor(ss, off); }
  __shared__ float s1[4], s2[4];
  if ((tid&63)==0){ s1[tid>>6]=sum; s2[tid>>6]=ss; }
  __syncthreads();
  sum = s1[0]+s1[1]+s1[2]+s1[3];
  ss  = s2[0]+s2[1]+s2[2]+s2[3];
  const float inv = 1.f/6464.f;
  float mean = sum*inv;
  float var  = ss*inv - mean*mean;
  float rstd = rsqrtf(var + 1e-5f);
  for (int i=tid; i<101*64; i+=256){
    int nd=i>>6, c=i&63;
    int row = (nd<100) ? g*100+nd : NN+g;
    float v = (y[(size_t)row*DD + c] - mean)*rstd;
    o[(size_t)row*DD + c] = v;
    if (xin) xin[(size_t)row*HC + c] = v;
  }
}

__global__ void copy_c_o_k(const float* __restrict__ c_emb, float* __restrict__ o){
  int idx = blockIdx.x*256 + threadIdx.x;
  if (idx >= NG*DD) return;
  o[(size_t)NN*DD + idx] = c_emb[idx];
}

// ---------- final outputs ----------
__global__ void glob_k(const float* __restrict__ o, const float* __restrict__ c_emb,
                       float* __restrict__ gout){
  int g = blockIdx.x, c = threadIdx.x;
  float acc = 0.f;
  for (int t=0;t<100;t++) acc += o[(size_t)(g*100+t)*DD + c];
  gout[(size_t)g*192 + c]       = acc / 100.f;
  gout[(size_t)g*192 + 64 + c]  = o[(size_t)(NN+g)*DD + c];
  gout[(size_t)g*192 + 128 + c] = c_emb[(size_t)g*DD + c];
}
__global__ void ofinal_k(const float* __restrict__ o, const float* __restrict__ c_emb,
                         const int* __restrict__ batch, float* __restrict__ out){
  int idx = blockIdx.x*256 + threadIdx.x;
  if (idx >= NN*HC) return;
  int n = idx>>7, j = idx&127;
  out[idx] = (j<64) ? o[(size_t)n*DD + j] : c_emb[(size_t)batch[n]*DD + (j-64)];
}

static inline int cdiv(int a, int b){ return (a+b-1)/b; }

static inline void gemm_mfma(int N, const float* A, const float* A2, int M, int K, int lda,
                             const unsigned short* Wt, const float* bias, int act,
                             const float* res, const float* res2, int rstride,
                             float* out, int ostride, hipStream_t st){
  int KC = (K > 128) ? 128 : K;
  int KPc = KC + 8;
  size_t sh = (size_t)(N*KPc + 64*KPc) * 2;
  int grid = cdiv(M, 64);
  if (N == 64)
    gemm_mfma_k<64><<<grid,256,sh,st>>>(A,A2,M,K,lda,Wt,bias,act,res,res2,rstride,out,ostride);
  else if (N == 128)
    gemm_mfma_k<128><<<grid,256,sh,st>>>(A,A2,M,K,lda,Wt,bias,act,res,res2,rstride,out,ostride);
  else
    gemm_mfma_k<256><<<grid,256,sh,st>>>(A,A2,M,K,lda,Wt,bias,act,res,res2,rstride,out,ostride);
}

extern "C" void kernel_launch(void* const* d_in, const int* in_sizes, int n_in,
                              void* d_out, int out_size, void* d_ws, size_t ws_size,
                              hipStream_t stream){
  (void)in_sizes; (void)n_in; (void)out_size;
  const float* x         = (const float*)d_in[0];
  const float* edge_attr = (const float*)d_in[1];
  const float* cond      = (const float*)d_in[2];
  const int*   edge_index= (const int*)  d_in[3];
  const int*   batch     = (const int*)  d_in[4];
  const float* xW1=(const float*)d_in[5],  *xb1=(const float*)d_in[6],
             * xW2=(const float*)d_in[7],  *xb2=(const float*)d_in[8],
             * xW3=(const float*)d_in[9],  *xb3=(const float*)d_in[10];
  const float* eW1=(const float*)d_in[11], *eb1=(const float*)d_in[12],
             * eW2=(const float*)d_in[13], *eb2=(const float*)d_in[14],
             * eW3=(const float*)d_in[15], *eb3=(const float*)d_in[16];
  const float* cW1=(const float*)d_in[17], *cb1=(const float*)d_in[18],
             * cW2=(const float*)d_in[19], *cb2=(const float*)d_in[20],
             * cW3=(const float*)d_in[21], *cb3=(const float*)d_in[22];
  const float* gen_W=(const float*)d_in[23];
  const float* trWq=(const float*)d_in[24], *trbq=(const float*)d_in[25];
  const float* trWk=(const float*)d_in[26], *trbk=(const float*)d_in[27];
  const float* trWv=(const float*)d_in[28], *trbv=(const float*)d_in[29];
  const float* trWe=(const float*)d_in[30];
  const float* trWs=(const float*)d_in[31], *trbs=(const float*)d_in[32];
  const float* linW=(const float*)d_in[33], *linb=(const float*)d_in[34];
  const float* ffW1=(const float*)d_in[35], *ffb1=(const float*)d_in[36];
  const float* ffW2=(const float*)d_in[37], *ffb2=(const float*)d_in[38];
  float* out = (float*)d_out;

  // ---- workspace carve-up (floats) ----
  float* ws = (float*)d_ws;
  size_t off = 0;
  auto alloc = [&](size_t n)->float*{ float* p = ws + off; off += (n + 63) & ~(size_t)63; return p; };
  int*      srcA  = (int*)alloc(EAUG);
  int*      dstA  = (int*)alloc(EAUG);
  int*      cnt   = (int*)alloc(NAUG);
  int*      rowptr= (int*)alloc(NAUG+1);
  int*      cursor= (int*)alloc(NAUG);
  int*      eid   = (int*)alloc(EAUG);
  int*      esrc  = (int*)alloc(EAUG);
  int*      epos  = (int*)alloc(EAUG);
  int*      pdst  = (int*)alloc(EAUG);
  unsigned short* aug_b = (unsigned short*)alloc((size_t)EAUG*DD/2);  // bf16 CSR-permuted
  float*    o     = alloc((size_t)NAUG*DD);
  float*    c_emb = alloc((size_t)NG*DD);
  float*    ybuf  = alloc((size_t)NAUG*DD);
  float*    aggsum= alloc((size_t)NAUG*DD);
  float*    xin   = alloc((size_t)NAUG*HC);
  float*    xqkvs = alloc((size_t)NAUG*QS);
  float*    toutb = alloc((size_t)NAUG*HC);
  float*    t1    = alloc((size_t)NAUG*HC);
  float*    wbuf  = alloc((size_t)NAUG*HC);
  float*    ffh   = alloc((size_t)NAUG*256);
  float2*   lgb   = (float2*)alloc((size_t)EAUG*2);
  unsigned short* warena = (unsigned short*)alloc(210432);   // bf16 weights (39 jobs)
  unsigned short* qweb   = (unsigned short*)alloc(3*128*136/2 + 64);
  float*    bqeb  = alloc(3*128);
  if (off*sizeof(float) > ws_size) return;

  const unsigned short* wptr[39];
  int wblk = 0;
  { size_t woff = 0;
    for (int j = 0; j < 39; j++){
      wptr[j] = warena + woff;
      int e = WTAB_H[j][3]*WTAB_H[j][4];
      woff += (size_t)e;
      wblk += cdiv(e, 256);
    } }

  // ---- weight conversion + combined qe weight ----
  WPtrs wp;
  wp.p[0]=trWq; wp.p[1]=trWk; wp.p[2]=trWv; wp.p[3]=trWs; wp.p[4]=gen_W;
  wp.p[5]=linW; wp.p[6]=ffW1; wp.p[7]=ffW2; wp.p[8]=trWe;
  wp.p[9]=xW1; wp.p[10]=xW2; wp.p[11]=xW3;
  wp.p[12]=eW1; wp.p[13]=eW2; wp.p[14]=eW3;
  wp.p[15]=cW1; wp.p[16]=cW2; wp.p[17]=cW3;
  wconv_all_k<<<wblk,256,0,stream>>>(wp, warena);
  qecomb_k<<<dim3(128,3),128,0,stream>>>(trWq, trbq, trWe, qweb, bqeb);

  // ---- setup: edges + CSR ----
  hipMemsetAsync(cnt, 0, sizeof(int)*NAUG, stream);
  hipMemsetAsync(cursor, 0, sizeof(int)*NAUG, stream);
  build_edges_k<<<cdiv(EAUG,256),256,0,stream>>>(edge_index, batch, srcA, dstA, cnt);
  scan_k<<<1,1024,0,stream>>>(cnt, rowptr);
  scatter_k<<<cdiv(EAUG,256),256,0,stream>>>(dstA, rowptr, cursor, eid, epos);
  fill_esrc_k<<<cdiv(EAUG,256),256,0,stream>>>(eid, srcA, esrc);
  fill_pdst_k<<<cdiv(NAUG,16),256,0,stream>>>(rowptr, pdst);

  // ---- input MLPs (edge MLP -> bf16 CSR-permuted) + pads / loop-attr ----
  mlp3_mfma_k<<<cdiv(NN,64),256,0,stream>>>(x,        NN, 32, wptr[30],wptr[31],wptr[32], xb1,xb2,xb3, nullptr, o,     nullptr);
  mlp3_mfma_k<<<cdiv(NG,64),256,0,stream>>>(cond,     NG, 32, wptr[36],wptr[37],wptr[38], cb1,cb2,cb3, nullptr, c_emb, nullptr);
  mlp3_mfma_k<<<cdiv(NE,64),256,0,stream>>>(edge_attr,NE, 16, wptr[33],wptr[34],wptr[35], eb1,eb2,eb3, epos,    nullptr, aug_b);
  set_ep_k<<<cdiv(2*NN*DD,256),256,0,stream>>>(epos, aug_b);
  loopmean_k<<<cdiv(NAUG,16),256,0,stream>>>(rowptr, epos, aug_b);
  copy_c_o_k<<<cdiv(NG*DD,256),256,0,stream>>>(c_emb, o);
  copy_o_xin_k<<<cdiv(NAUG*DD,256),256,0,stream>>>(o, xin);

  // ---- layers ----
  for (int L=0; L<3; L++){
    const float* lb_i = linb + (size_t)L*DD;
    const float* f1b  = ffb1 + (size_t)L*256;
    const float* f2b  = ffb2 + (size_t)L*DD;
    const unsigned short* genT = wptr[12+L], *linT = wptr[15+L], *ff1T = wptr[18+L], *ff2T = wptr[21+L];
    PW5 pw5;
    pw5.w[0]=wptr[0+L]; pw5.w[1]=wptr[3+L]; pw5.w[2]=wptr[6+L]; pw5.w[3]=wptr[9+L];
    pw5.w[4]=qweb + (size_t)L*128*136;
    pw5.b[0]=trbq+(size_t)L*HC; pw5.b[1]=trbk+(size_t)L*HC;
    pw5.b[2]=trbv+(size_t)L*HC; pw5.b[3]=trbs+(size_t)L*HC;
    pw5.b[4]=bqeb + (size_t)L*128;
    PW2 pwT; pwT.w[0]=wptr[24+2*L]; pwT.w[1]=wptr[25+2*L];

    msg_graph_k<<<2*NG,512,0,stream>>>(o, aug_b, rowptr, esrc, aggsum);
    gemm_mfma( 64, aggsum, o, NAUG, 64, 64, genT, nullptr, 0, nullptr, nullptr, 0, xin+64, HC, stream);
    qkvs5_k<<<dim3(cdiv(NAUG,64),5),256,0,stream>>>(xin, NAUG, pw5, xqkvs);
    scoredot_k<<<cdiv(EAUG,32),512,0,stream>>>(xqkvs, aug_b, pdst, esrc, lgb);
    attn_lite_k<<<2*NG,512,0,stream>>>(xqkvs, lgb, aug_b, rowptr, esrc, t1, wbuf);
    tout2_k<<<dim3(cdiv(NAUG,64),2),256,0,stream>>>(wbuf, NAUG, pwT, t1, xqkvs, toutb);
    gemm_mfma( 64, toutb, nullptr, NAUG, 128, 128, linT, lb_i, 0, o, nullptr, DD, ybuf, DD, stream);
    ln_k<<<NG,256,0,stream>>>(ybuf, o, nullptr);
    gemm_mfma(256, o,   nullptr, NAUG,  64,  64, ff1T, f1b, 1, nullptr, nullptr, 0, ffh, 256, stream);
    gemm_mfma( 64, ffh, nullptr, NAUG, 256, 256, ff2T, f2b, 0, o, nullptr, DD, ybuf, DD, stream);
    ln_k<<<NG,256,0,stream>>>(ybuf, o, xin);
  }

  // ---- outputs ----
  glob_k<<<NG,64,0,stream>>>(o, c_emb, out + (size_t)NN*HC);
  ofinal_k<<<cdiv(NN*HC,256),256,0,stream>>>(o, c_emb, batch, out);
}

// Round 11
// 1240.073 us; speedup vs baseline: 1.0786x; 1.0346x over previous
//
#include <hip/hip_runtime.h>
#include <cstddef>

#define NN   20000          // real nodes
#define NG   200            // graphs / virtual nodes
#define NE   320000         // original edges
#define NAUG 20200          // NN + NG
#define NE2  360000         // NE + 2*NN  (edges before self-loops)
#define EAUG 380200         // NE2 + NAUG
#define DD   64             // NUM_EMB
#define HC   128            // HEADS * NUM_EMB
#define QS   640            // xqkvs row stride: [q|k|v|xs|qe]

typedef float  f32x4 __attribute__((ext_vector_type(4)));
typedef short  s16x8 __attribute__((ext_vector_type(8)));

static __device__ __forceinline__ unsigned short bf16r(float f){
  unsigned u = __float_as_uint(f);
  u += 0x7FFFu + ((u >> 16) & 1u);
  return (unsigned short)(u >> 16);
}
static __device__ __forceinline__ float4 b2f4(ushort4 u){
  return make_float4(__uint_as_float((unsigned)u.x << 16),
                     __uint_as_float((unsigned)u.y << 16),
                     __uint_as_float((unsigned)u.z << 16),
                     __uint_as_float((unsigned)u.w << 16));
}
static __device__ __forceinline__ ushort4 f2b4(float4 v){
  ushort4 s; s.x=bf16r(v.x); s.y=bf16r(v.y); s.z=bf16r(v.z); s.w=bf16r(v.w); return s;
}
static __device__ __forceinline__ float d4(float4 a, float4 b){
  return a.x*b.x + a.y*b.y + a.z*b.z + a.w*b.w;
}
static __device__ __forceinline__ float4 f4a(float4 a, float4 b, float t){
  return make_float4(a.x + b.x*t, a.y + b.y*t, a.z + b.z*t, a.w + b.w*t);
}
static __device__ __forceinline__ float4 f4s(float4 a, float s){
  return make_float4(a.x*s, a.y*s, a.z*s, a.w*s);
}

// =====================================================================
// Weight pre-conversion: fp32 -> bf16, transposed to Bt[n][k], stride KP=K+8
// =====================================================================
#define WTAB_INIT { \
  {0,0,128,128,136,128,0},{0,0,128,128,136,128,16384},{0,0,128,128,136,128,32768}, \
  {1,0,128,128,136,128,0},{1,0,128,128,136,128,16384},{1,0,128,128,136,128,32768}, \
  {2,0,128,128,136,128,0},{2,0,128,128,136,128,16384},{2,0,128,128,136,128,32768}, \
  {3,0,128,128,136,128,0},{3,0,128,128,136,128,16384},{3,0,128,128,136,128,32768}, \
  {4,0,64,64,72,64,0},{4,0,64,64,72,64,4096},{4,0,64,64,72,64,8192}, \
  {5,0,128,64,136,64,0},{5,0,128,64,136,64,8192},{5,0,128,64,136,64,16384}, \
  {6,0,64,256,72,256,0},{6,0,64,256,72,256,16384},{6,0,64,256,72,256,32768}, \
  {7,0,256,64,264,64,0},{7,0,256,64,264,64,16384},{7,0,256,64,264,64,32768}, \
  {8,0,64,64,72,128,0},{8,0,64,64,72,128,64},{8,0,64,64,72,128,8192},{8,0,64,64,72,128,8256},{8,0,64,64,72,128,16384},{8,0,64,64,72,128,16448}, \
  {9,0,32,64,40,64,0},{10,0,64,64,72,64,0},{11,0,64,64,72,64,0}, \
  {12,0,16,64,40,64,0},{13,0,64,64,72,64,0},{14,0,64,64,72,64,0}, \
  {15,0,32,64,40,64,0},{16,0,64,64,72,64,0},{17,0,64,64,72,64,0} }

static const int WTAB_H[39][7] = WTAB_INIT;
__device__ static const int WTAB_D[39][7] = WTAB_INIT;

struct WPtrs { const float* p[18]; };

__global__ void wconv_all_k(WPtrs wp, unsigned short* __restrict__ outbase){
  int b = blockIdx.x;
  int acc = 0; unsigned ooff = 0;
  #pragma unroll 1
  for (int j = 0; j < 39; j++){
    int e  = WTAB_D[j][3] * WTAB_D[j][4];
    int nb = (e + 255) >> 8;
    if (b < acc + nb){
      int idx = (b - acc)*256 + threadIdx.x;
      if (idx < e){
        int KP = WTAB_D[j][4];
        int n = idx / KP, k = idx % KP;
        float v = 0.f;
        if (k < WTAB_D[j][2]){
          const float* s = wp.p[WTAB_D[j][0]];
          int st = WTAB_D[j][5], so = WTAB_D[j][6];
          v = (WTAB_D[j][1] == 0) ? s[(size_t)so + (size_t)k*st + n]
                                  : s[(size_t)so + (size_t)n*st + k];
        }
        outbase[ooff + idx] = bf16r(v);
      }
      return;
    }
    acc += nb; ooff += (unsigned)e;
  }
}

// =====================================================================
// Combined qe weight
// =====================================================================
__global__ void qecomb_k(const float* __restrict__ trWq, const float* __restrict__ trbq,
                         const float* __restrict__ trWe,
                         unsigned short* __restrict__ qweb, float* __restrict__ bqeb){
  int L = blockIdx.y;
  int n = blockIdx.x;
  int i = threadIdx.x;
  int h = n >> 6, d = n & 63;
  const float* Wq = trWq + (size_t)L*128*128;
  const float* We = trWe + (size_t)L*64*128;
  float acc = 0.f;
  for (int c = 0; c < 64; c++)
    acc += Wq[(size_t)i*128 + h*64 + c] * We[(size_t)d*128 + h*64 + c];
  qweb[(size_t)L*128*136 + n*136 + i] = bf16r(acc);
  if (i < 8) qweb[(size_t)L*128*136 + n*136 + 128 + i] = 0;
  if (i == 0){
    const float* bq = trbq + (size_t)L*128;
    float b = 0.f;
    for (int c = 0; c < 64; c++) b += bq[h*64 + c] * We[(size_t)d*128 + h*64 + c];
    bqeb[L*128 + n] = b;
  }
}

// =====================================================================
// Generic MFMA GEMM (template N)
// =====================================================================
template<int NT>
__launch_bounds__(256)
__global__ void gemm_mfma_k(const float* __restrict__ A, const float* __restrict__ A2,
                            int M, int K, int lda,
                            const unsigned short* __restrict__ WtG,
                            const float* __restrict__ bias, int act,
                            const float* __restrict__ res, const float* __restrict__ res2,
                            int rstride, float* __restrict__ out, int ostride){
  extern __shared__ unsigned short smem[];
  const int KC  = (K > 128) ? 128 : K;
  const int KPc = KC + 8;
  const int KP  = K + 8;
  unsigned short* Wts  = smem;
  unsigned short* Asub = smem + NT*KPc;
  const int tid = threadIdx.x;
  const int wid = tid >> 6, lane = tid & 63;
  const int lrow = lane & 15, quad = lane >> 4;
  const int m0 = blockIdx.x * 64;
  f32x4 acc[NT/16];
  #pragma unroll
  for (int t = 0; t < NT/16; t++) acc[t] = (f32x4){0.f,0.f,0.f,0.f};

  for (int k0 = 0; k0 < K; k0 += KC){
    const int wv = NT*KPc/8, wrow = KPc/8;
    for (int i = tid; i < wv; i += 256){
      int n = i / wrow, c8 = i % wrow;
      *(uint4*)&Wts[n*KPc + c8*8] = *(const uint4*)&WtG[(size_t)n*KP + k0 + c8*8];
    }
    const int av = 64*KC/4, arow = KC/4;
    for (int i = tid; i < av; i += 256){
      int r = i / arow, c4i = i % arow;
      int m = m0 + r, k = k0 + c4i*4;
      float4 v = make_float4(0.f,0.f,0.f,0.f);
      if (m < M){
        v = *(const float4*)(A + (size_t)m*lda + k);
        if (A2){ float4 w = *(const float4*)(A2 + (size_t)m*lda + k);
                 v.x += w.x; v.y += w.y; v.z += w.z; v.w += w.w; }
      }
      *(ushort4*)&Asub[r*KPc + c4i*4] = f2b4(v);
    }
    __syncthreads();
    const int ksteps = KC >> 5;
    for (int ks = 0; ks < ksteps; ks++){
      s16x8 a = *(const s16x8*)&Asub[(wid*16 + lrow)*KPc + ks*32 + quad*8];
      #pragma unroll
      for (int nt = 0; nt < NT/16; nt++){
        s16x8 b = *(const s16x8*)&Wts[(nt*16 + lrow)*KPc + ks*32 + quad*8];
        acc[nt] = __builtin_amdgcn_mfma_f32_16x16x32_bf16(a, b, acc[nt], 0, 0, 0);
      }
    }
    __syncthreads();
  }

  const int mb = m0 + wid*16 + quad*4;
  #pragma unroll
  for (int nt = 0; nt < NT/16; nt++){
    int n = nt*16 + lrow;
    #pragma unroll
    for (int r = 0; r < 4; r++){
      int m = mb + r;
      if (m < M){
        float v = acc[nt][r];
        if (bias) v += bias[n];
        if (act)  v = v > 0.f ? v : 0.01f*v;
        if (res)  v += res [(size_t)m*rstride + n];
        if (res2) v += res2[(size_t)m*rstride + n];
        out[(size_t)m*ostride + n] = v;
      }
    }
  }
}

// =====================================================================
// Batched QKVS+QE GEMM
// =====================================================================
struct PW5 { const unsigned short* w[5]; const float* b[5]; };

__launch_bounds__(256)
__global__ void qkvs5_k(const float* __restrict__ A, int M, PW5 pw,
                        float* __restrict__ out){
  __shared__ __align__(16) unsigned short Wts[128*136];
  __shared__ __align__(16) unsigned short Asub[64*136];
  const unsigned short* WtG = pw.w[blockIdx.y];
  const float* bias = pw.b[blockIdx.y];
  const int tid = threadIdx.x;
  const int wid = tid >> 6, lane = tid & 63;
  const int lrow = lane & 15, quad = lane >> 4;
  const int m0 = blockIdx.x * 64;
  for (int i = tid; i < 128*17; i += 256){
    int n = i/17, c8 = i%17;
    *(uint4*)&Wts[n*136 + c8*8] = *(const uint4*)&WtG[(size_t)n*136 + c8*8];
  }
  for (int i = tid; i < 64*32; i += 256){
    int r = i >> 5, c4 = (i & 31)*4;
    int m = m0 + r;
    float4 v = make_float4(0.f,0.f,0.f,0.f);
    if (m < M) v = *(const float4*)(A + (size_t)m*128 + c4);
    *(ushort4*)&Asub[r*136 + c4] = f2b4(v);
  }
  __syncthreads();
  f32x4 acc[8];
  #pragma unroll
  for (int t=0;t<8;t++) acc[t] = (f32x4){0.f,0.f,0.f,0.f};
  #pragma unroll
  for (int ks = 0; ks < 4; ks++){
    s16x8 a = *(const s16x8*)&Asub[(wid*16 + lrow)*136 + ks*32 + quad*8];
    #pragma unroll
    for (int nt = 0; nt < 8; nt++){
      s16x8 b = *(const s16x8*)&Wts[(nt*16 + lrow)*136 + ks*32 + quad*8];
      acc[nt] = __builtin_amdgcn_mfma_f32_16x16x32_bf16(a, b, acc[nt], 0, 0, 0);
    }
  }
  const int mb = m0 + wid*16 + quad*4;
  const int yoff = blockIdx.y*128;
  #pragma unroll
  for (int nt = 0; nt < 8; nt++){
    int n = nt*16 + lrow;
    #pragma unroll
    for (int r = 0; r < 4; r++){
      int m = mb + r;
      if (m < M) out[(size_t)m*QS + yoff + n] = acc[nt][r] + bias[n];
    }
  }
}

// =====================================================================
// Batched per-head 64x64 GEMM (tout)
// =====================================================================
struct PW2 { const unsigned short* w[2]; };

__launch_bounds__(256)
__global__ void tout2_k(const float* __restrict__ wv, int M, PW2 pw,
                        const float* __restrict__ t1, const float* __restrict__ qkvs,
                        float* __restrict__ tout){
  __shared__ __align__(16) unsigned short Wts[64*72];
  __shared__ __align__(16) unsigned short Asub[64*72];
  const unsigned short* WtG = pw.w[blockIdx.y];
  const int tid = threadIdx.x;
  const int wid = tid >> 6, lane = tid & 63;
  const int lrow = lane & 15, quad = lane >> 4;
  const int m0 = blockIdx.x * 64;
  const int yoff = blockIdx.y * 64;
  for (int i = tid; i < 64*9; i += 256){
    int n = i/9, c8 = i%9;
    *(uint4*)&Wts[n*72 + c8*8] = *(const uint4*)&WtG[(size_t)n*72 + c8*8];
  }
  for (int i = tid; i < 64*16; i += 256){
    int r = i >> 4, c4 = (i & 15)*4;
    int m = m0 + r;
    float4 v = make_float4(0.f,0.f,0.f,0.f);
    if (m < M) v = *(const float4*)(wv + (size_t)m*HC + yoff + c4);
    *(ushort4*)&Asub[r*72 + c4] = f2b4(v);
  }
  __syncthreads();
  f32x4 acc[4];
  #pragma unroll
  for (int t=0;t<4;t++) acc[t] = (f32x4){0.f,0.f,0.f,0.f};
  #pragma unroll
  for (int ks = 0; ks < 2; ks++){
    s16x8 a = *(const s16x8*)&Asub[(wid*16 + lrow)*72 + ks*32 + quad*8];
    #pragma unroll
    for (int nt = 0; nt < 4; nt++){
      s16x8 b = *(const s16x8*)&Wts[(nt*16 + lrow)*72 + ks*32 + quad*8];
      acc[nt] = __builtin_amdgcn_mfma_f32_16x16x32_bf16(a, b, acc[nt], 0, 0, 0);
    }
  }
  const int mb = m0 + wid*16 + quad*4;
  #pragma unroll
  for (int nt = 0; nt < 4; nt++){
    int n = nt*16 + lrow;
    #pragma unroll
    for (int r = 0; r < 4; r++){
      int m = mb + r;
      if (m < M)
        tout[(size_t)m*HC + yoff + n] = acc[nt][r]
          + t1[(size_t)m*HC + yoff + n] + qkvs[(size_t)m*QS + 384 + yoff + n];
    }
  }
}

// =====================================================================
// Fused 3-layer MLP via MFMA — wave-private tiles, single barrier.
// =====================================================================
__launch_bounds__(256)
__global__ void mlp3_mfma_k(const float* __restrict__ X, int M, int Din,
                            const unsigned short* __restrict__ w1t,
                            const unsigned short* __restrict__ w2t,
                            const unsigned short* __restrict__ w3t,
                            const float* __restrict__ b1, const float* __restrict__ b2,
                            const float* __restrict__ b3,
                            const int* __restrict__ perm, float* __restrict__ out,
                            unsigned short* __restrict__ outb){
  __shared__ __align__(16) unsigned short W1s[64*40], W2s[64*72], W3s[64*72];
  __shared__ __align__(16) unsigned short xs[4][16*40];
  __shared__ __align__(16) unsigned short hs[4][16*72];
  __shared__ float bsh[192];
  const int tid = threadIdx.x;
  const int wid = tid >> 6, lane = tid & 63;
  const int lrow = lane & 15, quad = lane >> 4;
  for (int i = tid; i < 320; i += 256)  *(uint4*)&W1s[i*8] = *(const uint4*)&w1t[i*8];
  for (int i = tid; i < 576; i += 256){ *(uint4*)&W2s[i*8] = *(const uint4*)&w2t[i*8];
                                        *(uint4*)&W3s[i*8] = *(const uint4*)&w3t[i*8]; }
  if (tid < 64){ bsh[tid] = b1[tid]; bsh[64+tid] = b2[tid]; bsh[128+tid] = b3[tid]; }

  const int m0 = blockIdx.x*64 + wid*16;
  {
    int r = lane >> 2, c8 = (lane & 3) * 8;
    int m = m0 + r;
    float4 va = make_float4(0.f,0.f,0.f,0.f), vb = va;
    if (m < M && c8 < Din){
      va = *(const float4*)(X + (size_t)m*Din + c8);
      vb = *(const float4*)(X + (size_t)m*Din + c8 + 4);
    }
    *(ushort4*)&xs[wid][r*40 + c8]     = f2b4(va);
    *(ushort4*)&xs[wid][r*40 + c8 + 4] = f2b4(vb);
  }
  __syncthreads();

  f32x4 acc[4];
  #pragma unroll
  for (int t = 0; t < 4; t++) acc[t] = (f32x4){0.f,0.f,0.f,0.f};
  {
    s16x8 a = *(const s16x8*)&xs[wid][lrow*40 + quad*8];
    #pragma unroll
    for (int nt = 0; nt < 4; nt++){
      s16x8 b = *(const s16x8*)&W1s[(nt*16 + lrow)*40 + quad*8];
      acc[nt] = __builtin_amdgcn_mfma_f32_16x16x32_bf16(a, b, acc[nt], 0, 0, 0);
    }
  }
  #pragma unroll
  for (int nt = 0; nt < 4; nt++){
    int n = nt*16 + lrow;
    #pragma unroll
    for (int r = 0; r < 4; r++){
      float v = acc[nt][r] + bsh[n];
      v = v > 0.f ? v : 0.01f*v;
      hs[wid][(quad*4 + r)*72 + n] = bf16r(v);
    }
  }
  #pragma unroll
  for (int t = 0; t < 4; t++) acc[t] = (f32x4){0.f,0.f,0.f,0.f};
  #pragma unroll
  for (int ks = 0; ks < 2; ks++){
    s16x8 a = *(const s16x8*)&hs[wid][lrow*72 + ks*32 + quad*8];
    #pragma unroll
    for (int nt = 0; nt < 4; nt++){
      s16x8 b = *(const s16x8*)&W2s[(nt*16 + lrow)*72 + ks*32 + quad*8];
      acc[nt] = __builtin_amdgcn_mfma_f32_16x16x32_bf16(a, b, acc[nt], 0, 0, 0);
    }
  }
  #pragma unroll
  for (int nt = 0; nt < 4; nt++){
    int n = nt*16 + lrow;
    #pragma unroll
    for (int r = 0; r < 4; r++){
      float v = acc[nt][r] + bsh[64 + n];
      v = v > 0.f ? v : 0.01f*v;
      hs[wid][(quad*4 + r)*72 + n] = bf16r(v);
    }
  }
  #pragma unroll
  for (int t = 0; t < 4; t++) acc[t] = (f32x4){0.f,0.f,0.f,0.f};
  #pragma unroll
  for (int ks = 0; ks < 2; ks++){
    s16x8 a = *(const s16x8*)&hs[wid][lrow*72 + ks*32 + quad*8];
    #pragma unroll
    for (int nt = 0; nt < 4; nt++){
      s16x8 b = *(const s16x8*)&W3s[(nt*16 + lrow)*72 + ks*32 + quad*8];
      acc[nt] = __builtin_amdgcn_mfma_f32_16x16x32_bf16(a, b, acc[nt], 0, 0, 0);
    }
  }
  #pragma unroll
  for (int nt = 0; nt < 4; nt++){
    int n = nt*16 + lrow;
    #pragma unroll
    for (int r = 0; r < 4; r++){
      int m = m0 + quad*4 + r;
      if (m < M){
        int orow = perm ? perm[m] : m;
        float v = acc[nt][r] + bsh[128 + n];
        if (outb) outb[(size_t)orow*64 + n] = bf16r(v);
        else      out [(size_t)orow*64 + n] = v;
      }
    }
  }
}

// ---------- build augmented edge list (+degree count) ----------
__global__ void build_edges_k(const int* __restrict__ ei, const int* __restrict__ batch,
                              int* __restrict__ srcA, int* __restrict__ dstA,
                              int* __restrict__ cnt){
  int idx = blockIdx.x*256 + threadIdx.x;
  if (idx >= EAUG) return;
  int s, d;
  if (idx < NE)          { s = ei[idx];              d = ei[NE+idx]; }
  else if (idx < NE+NN)  { int i = idx-NE;           s = i;            d = batch[i]+NN; }
  else if (idx < NE2)    { int i = idx-(NE+NN);      s = batch[i]+NN;  d = i; }
  else                   { int i = idx-NE2;          s = i;            d = i; }
  srcA[idx]=s; dstA[idx]=d;
  atomicAdd(&cnt[d], 1);
}

__global__ void scan_k(const int* __restrict__ cnt, int* __restrict__ rowptr){
  __shared__ int part[1024];
  int tid = threadIdx.x;
  const int per = (NAUG + 1023) / 1024;
  int base = tid * per;
  int s = 0;
  for (int i=0;i<per;i++){ int idx=base+i; if (idx<NAUG) s += cnt[idx]; }
  part[tid] = s;
  __syncthreads();
  for (int off=1; off<1024; off<<=1){
    int v = (tid>=off) ? part[tid-off] : 0;
    __syncthreads();
    part[tid] += v;
    __syncthreads();
  }
  int run = (tid==0) ? 0 : part[tid-1];
  for (int i=0;i<per;i++){
    int idx=base+i;
    if (idx<NAUG){ rowptr[idx]=run; run += cnt[idx]; }
  }
  if (tid==0) rowptr[NAUG] = EAUG;
}

__global__ void scatter_k(const int* __restrict__ dstA,
                          const int* __restrict__ rowptr, int* __restrict__ cursor,
                          int* __restrict__ eid, int* __restrict__ epos){
  int e = blockIdx.x*256 + threadIdx.x;
  if (e >= EAUG) return;
  int d = dstA[e];
  int pos = rowptr[d] + atomicAdd(&cursor[d], 1);
  eid[pos] = e;
  epos[e]  = pos;
}

__global__ void fill_esrc_k(const int* __restrict__ eid, const int* __restrict__ srcA,
                            int* __restrict__ esrc){
  int p = blockIdx.x*256 + threadIdx.x;
  if (p < EAUG) esrc[p] = srcA[eid[p]];
}

__launch_bounds__(256)
__global__ void fill_pdst_k(const int* __restrict__ rowptr, int* __restrict__ pdst){
  int d = blockIdx.x*16 + (threadIdx.x >> 4);
  if (d >= NAUG) return;
  int lane = threadIdx.x & 15;
  int beg = rowptr[d], end = rowptr[d+1];
  for (int p = beg + lane; p < end; p += 16) pdst[p] = d;
}

// ---------- one-hot padding rows of aug (CSR-permuted, bf16) ----------
__global__ void set_ep_k(const int* __restrict__ epos, unsigned short* __restrict__ aug_b){
  int idx = blockIdx.x*256 + threadIdx.x;
  if (idx >= 2*NN*DD) return;
  int i = idx >> 6, c = idx & 63;
  aug_b[(size_t)epos[NE + i]*DD + c] = (c==0) ? (unsigned short)0x3F80 : (unsigned short)0;
}

// ---------- loop_attr ----------
__launch_bounds__(256)
__global__ void loopmean_k(const int* __restrict__ rowptr, const int* __restrict__ epos,
                           unsigned short* __restrict__ aug_b){
  int tid = threadIdx.x;
  int d = blockIdx.x*16 + (tid>>4);
  if (d >= NAUG) return;
  int t4 = (tid & 15)*4;
  int beg = rowptr[d], end = rowptr[d+1];
  int sp = epos[NE2 + d];
  float4 s = make_float4(0.f,0.f,0.f,0.f);
  for (int p=beg; p<end; p++){
    float4 a = b2f4(*(const ushort4*)(aug_b + (size_t)p*DD + t4));
    float w = (p == sp) ? 0.f : 1.f;
    s.x += w*a.x; s.y += w*a.y; s.z += w*a.z; s.w += w*a.w;
  }
  int n = end - beg - 1;
  float cv = (n < 1) ? 1.f : (float)n;
  *(ushort4*)(aug_b + (size_t)sp*DD + t4) = f2b4(f4s(s, 1.f/cv));
}

// =====================================================================
// Per-graph CSR message aggregation: 4 blocks/graph
// =====================================================================
__launch_bounds__(512)
__global__ void msg_graph_k(const float* __restrict__ o, const unsigned short* __restrict__ aug_b,
                            const int* __restrict__ rowptr,
                            const int* __restrict__ esrc, float* __restrict__ aggsum){
  __shared__ __align__(16) float OS[101*72];
  __shared__ unsigned char EL[3072];
  const int g = blockIdx.x >> 2, quarter = blockIdx.x & 3;
  const int tid = threadIdx.x;
  for (int i = tid; i < 101*16; i += 512){
    int ln = i >> 4, c4 = (i & 15)*4;
    int row = (ln < 100) ? g*100 + ln : NN + g;
    *(float4*)&OS[ln*72 + c4] = *(const float4*)(o + (size_t)row*DD + c4);
  }
  const int baseA = rowptr[g*100];
  const int lenA  = rowptr[g*100 + 100] - baseA;
  const int baseB = rowptr[NN + g];
  const int lenB  = rowptr[NN + g + 1] - baseB;
  const bool useL = (lenA + lenB) <= 3072;
  if (useL){
    for (int i = tid; i < lenA; i += 512){
      int s = esrc[baseA + i];
      EL[i] = (unsigned char)((s >= NN) ? 100 : (s - g*100));
    }
    for (int i = tid; i < lenB; i += 512){
      int s = esrc[baseB + i];
      EL[lenA + i] = (unsigned char)((s >= NN) ? 100 : (s - g*100));
    }
  }
  __syncthreads();
  const int gr = tid >> 4, t4 = (tid & 15)*4;
  const int ld0 = quarter*26, ld1 = (quarter==3) ? 101 : (quarter+1)*26;
  for (int ld = ld0 + gr; ld < ld1; ld += 32){
    int d, pbeg, pend, eofs;
    if (ld < 100){ d = g*100 + ld; pbeg = rowptr[d]; pend = rowptr[d+1]; eofs = -baseA; }
    else         { d = NN + g;     pbeg = baseB;     pend = baseB + lenB; eofs = lenA - baseB; }
    float4 acc = make_float4(0.f,0.f,0.f,0.f);
    for (int p = pbeg; p < pend; p++){
      int ls;
      if (useL) ls = EL[p + eofs];
      else { int s = esrc[p]; ls = (s >= NN) ? 100 : (s - g*100); }
      float4 ov = *(const float4*)&OS[ls*72 + t4];
      float4 ae = b2f4(*(const ushort4*)(aug_b + (size_t)p*DD + t4));
      acc.x += fmaxf(ov.x+ae.x, 0.f) + 1e-7f;
      acc.y += fmaxf(ov.y+ae.y, 0.f) + 1e-7f;
      acc.z += fmaxf(ov.z+ae.z, 0.f) + 1e-7f;
      acc.w += fmaxf(ov.w+ae.w, 0.f) + 1e-7f;
    }
    *(float4*)(aggsum + (size_t)d*DD + t4) = acc;
  }
}

__global__ void copy_o_xin_k(const float* __restrict__ o, float* __restrict__ xin){
  int idx = blockIdx.x*256 + threadIdx.x;
  if (idx >= NAUG*DD) return;
  int n = idx >> 6, c = idx & 63;
  xin[(size_t)n*HC + c] = o[idx];
}

// =====================================================================
// Edge-parallel logits
// =====================================================================
__launch_bounds__(512)
__global__ void scoredot_k(const float* __restrict__ qkvs,
                           const unsigned short* __restrict__ aug_b,
                           const int* __restrict__ pdst, const int* __restrict__ esrc,
                           float2* __restrict__ lg){
  int p = blockIdx.x*32 + (threadIdx.x >> 4);
  if (p >= EAUG) return;
  int t4 = (threadIdx.x & 15)*4;
  int d = pdst[p], s = esrc[p];
  const float* qr = qkvs + (size_t)d*QS;
  const float* kr = qkvs + (size_t)s*QS + 128;
  float4 q0  = *(const float4*)(qr + t4);
  float4 q1  = *(const float4*)(qr + 64 + t4);
  float4 qe0 = *(const float4*)(qr + 512 + t4);
  float4 qe1 = *(const float4*)(qr + 576 + t4);
  float4 k0  = *(const float4*)(kr + t4);
  float4 k1  = *(const float4*)(kr + 64 + t4);
  float4 ae  = b2f4(*(const ushort4*)(aug_b + (size_t)p*DD + t4));
  float p0 = d4(q0,k0) + d4(qe0,ae);
  float p1 = d4(q1,k1) + d4(qe1,ae);
  p0 += __shfl_xor(p0,8); p0 += __shfl_xor(p0,4); p0 += __shfl_xor(p0,2); p0 += __shfl_xor(p0,1);
  p1 += __shfl_xor(p1,8); p1 += __shfl_xor(p1,4); p1 += __shfl_xor(p1,2); p1 += __shfl_xor(p1,1);
  if ((threadIdx.x & 15) == 0) lg[p] = make_float2(p0*0.125f, p1*0.125f);
}

// =====================================================================
// Attention (fused t1 + wbuf): 4 blocks/graph, V in LDS, two-pass per dst
// =====================================================================
__launch_bounds__(512)
__global__ void attn_lite_k(const float* __restrict__ qkvs, const float2* __restrict__ lg,
                            const unsigned short* __restrict__ aug_b,
                            const int* __restrict__ rowptr, const int* __restrict__ esrc,
                            float* __restrict__ t1, float* __restrict__ wbuf){
  __shared__ __align__(16) unsigned short VS[101*128];
  __shared__ unsigned char EL[3072];
  const int g = blockIdx.x >> 2, quarter = blockIdx.x & 3;
  const int tid = threadIdx.x;
  for (int i = tid; i < 101*32; i += 512){
    int ln = i >> 5, c4 = (i & 31)*4;
    int row = (ln < 100) ? g*100 + ln : NN + g;
    float4 v = *(const float4*)(qkvs + (size_t)row*QS + 256 + c4);
    *(ushort4*)&VS[ln*128 + c4] = f2b4(v);
  }
  const int baseA = rowptr[g*100];
  const int lenA  = rowptr[g*100 + 100] - baseA;
  const int baseB = rowptr[NN + g];
  const int lenB  = rowptr[NN + g + 1] - baseB;
  const bool useL = (lenA + lenB) <= 3072;
  if (useL){
    for (int i = tid; i < lenA; i += 512){
      int s = esrc[baseA + i];
      EL[i] = (unsigned char)((s >= NN) ? 100 : (s - g*100));
    }
    for (int i = tid; i < lenB; i += 512){
      int s = esrc[baseB + i];
      EL[lenA + i] = (unsigned char)((s >= NN) ? 100 : (s - g*100));
    }
  }
  __syncthreads();
  const int gr = tid >> 4, t4 = (tid & 15)*4;
  const int ld0 = quarter*26, ld1 = (quarter==3) ? 101 : (quarter+1)*26;
  for (int ld = ld0 + gr; ld < ld1; ld += 32){
    int d, pbeg, pend, eofs;
    if (ld < 100){ d = g*100 + ld; pbeg = rowptr[d]; pend = rowptr[d+1]; eofs = -baseA; }
    else         { d = NN + g;     pbeg = baseB;     pend = baseB + lenB; eofs = lenA - baseB; }
    // pass 1: segment max
    float m0 = -1e30f, m1 = -1e30f;
    for (int p = pbeg; p < pend; p++){
      float2 lv = lg[p];
      m0 = fmaxf(m0, lv.x); m1 = fmaxf(m1, lv.y);
    }
    // pass 2: accumulate exp(lg - m) * {V, ae}
    float l0 = 0.f, l1 = 0.f;
    float4 a0 = make_float4(0.f,0.f,0.f,0.f), a1 = a0, w0 = a0, w1 = a0;
    for (int p = pbeg; p < pend; p++){
      float2 lv = lg[p];
      int ls;
      if (useL) ls = EL[p + eofs];
      else { int s = esrc[p]; ls = (s >= NN) ? 100 : (s - g*100); }
      const unsigned short* vr = &VS[ls*128];
      float4 v0 = b2f4(*(const ushort4*)(vr + t4));
      float4 v1 = b2f4(*(const ushort4*)(vr + 64 + t4));
      float4 ae = b2f4(*(const ushort4*)(aug_b + (size_t)p*DD + t4));
      float e0 = __expf(lv.x - m0);
      float e1 = __expf(lv.y - m1);
      l0 += e0; a0 = f4a(a0, v0, e0); w0 = f4a(w0, ae, e0);
      l1 += e1; a1 = f4a(a1, v1, e1); w1 = f4a(w1, ae, e1);
    }
    float i0 = 1.f/(l0 + 1e-16f), i1 = 1.f/(l1 + 1e-16f);
    *(float4*)(t1   + (size_t)d*HC + t4)      = f4s(a0, i0);
    *(float4*)(t1   + (size_t)d*HC + 64 + t4) = f4s(a1, i1);
    *(float4*)(wbuf + (size_t)d*HC + t4)      = f4s(w0, i0);
    *(float4*)(wbuf + (size_t)d*HC + 64 + t4) = f4s(w1, i1);
  }
}

// ---------- per-graph layernorm ----------
__global__ void ln_k(const float* __restrict__ y, float* __restrict__ o,
                     float* __restrict__ xin){
  int g = blockIdx.x, tid = threadIdx.x;
  float sum=0.f, ss=0.f;
  for (int i=tid; i<101*64; i+=256){
    int nd=i>>6, c=i&63;
    int row = (nd<100) ? g*100+nd : NN+g;
    float v = y[(size_t)row*DD + c];
    sum += v; ss += v*v;
  }
  #pragma unroll
  for (int off=32; off; off>>=1){ sum += __shfl_xor(sum, off); ss += __shfl_xor(ss, off); }
  __shared__ float s1[4], s2[4];
  if ((tid&63)==0){ s1[tid>>6]=sum; s2[tid>>6]=ss; }
  __syncthreads();
  sum = s1[0]+s1[1]+s1[2]+s1[3];
  ss  = s2[0]+s2[1]+s2[2]+s2[3];
  const float inv = 1.f/6464.f;
  float mean = sum*inv;
  float var  = ss*inv - mean*mean;
  float rstd = rsqrtf(var + 1e-5f);
  for (int i=tid; i<101*64; i+=256){
    int nd=i>>6, c=i&63;
    int row = (nd<100) ? g*100+nd : NN+g;
    float v = (y[(size_t)row*DD + c] - mean)*rstd;
    o[(size_t)row*DD + c] = v;
    if (xin) xin[(size_t)row*HC + c] = v;
  }
}

__global__ void copy_c_o_k(const float* __restrict__ c_emb, float* __restrict__ o){
  int idx = blockIdx.x*256 + threadIdx.x;
  if (idx >= NG*DD) return;
  o[(size_t)NN*DD + idx] = c_emb[idx];
}

// ---------- final outputs ----------
__global__ void glob_k(const float* __restrict__ o, const float* __restrict__ c_emb,
                       float* __restrict__ gout){
  int g = blockIdx.x, c = threadIdx.x;
  float acc = 0.f;
  for (int t=0;t<100;t++) acc += o[(size_t)(g*100+t)*DD + c];
  gout[(size_t)g*192 + c]       = acc / 100.f;
  gout[(size_t)g*192 + 64 + c]  = o[(size_t)(NN+g)*DD + c];
  gout[(size_t)g*192 + 128 + c] = c_emb[(size_t)g*DD + c];
}
__global__ void ofinal_k(const float* __restrict__ o, const float* __restrict__ c_emb,
                         const int* __restrict__ batch, float* __restrict__ out){
  int idx = blockIdx.x*256 + threadIdx.x;
  if (idx >= NN*HC) return;
  int n = idx>>7, j = idx&127;
  out[idx] = (j<64) ? o[(size_t)n*DD + j] : c_emb[(size_t)batch[n]*DD + (j-64)];
}

static inline int cdiv(int a, int b){ return (a+b-1)/b; }

static inline void gemm_mfma(int N, const float* A, const float* A2, int M, int K, int lda,
                             const unsigned short* Wt, const float* bias, int act,
                             const float* res, const float* res2, int rstride,
                             float* out, int ostride, hipStream_t st){
  int KC = (K > 128) ? 128 : K;
  int KPc = KC + 8;
  size_t sh = (size_t)(N*KPc + 64*KPc) * 2;
  int grid = cdiv(M, 64);
  if (N == 64)
    gemm_mfma_k<64><<<grid,256,sh,st>>>(A,A2,M,K,lda,Wt,bias,act,res,res2,rstride,out,ostride);
  else if (N == 128)
    gemm_mfma_k<128><<<grid,256,sh,st>>>(A,A2,M,K,lda,Wt,bias,act,res,res2,rstride,out,ostride);
  else
    gemm_mfma_k<256><<<grid,256,sh,st>>>(A,A2,M,K,lda,Wt,bias,act,res,res2,rstride,out,ostride);
}

extern "C" void kernel_launch(void* const* d_in, const int* in_sizes, int n_in,
                              void* d_out, int out_size, void* d_ws, size_t ws_size,
                              hipStream_t stream){
  (void)in_sizes; (void)n_in; (void)out_size;
  const float* x         = (const float*)d_in[0];
  const float* edge_attr = (const float*)d_in[1];
  const float* cond      = (const float*)d_in[2];
  const int*   edge_index= (const int*)  d_in[3];
  const int*   batch     = (const int*)  d_in[4];
  const float* xW1=(const float*)d_in[5],  *xb1=(const float*)d_in[6],
             * xW2=(const float*)d_in[7],  *xb2=(const float*)d_in[8],
             * xW3=(const float*)d_in[9],  *xb3=(const float*)d_in[10];
  const float* eW1=(const float*)d_in[11], *eb1=(const float*)d_in[12],
             * eW2=(const float*)d_in[13], *eb2=(const float*)d_in[14],
             * eW3=(const float*)d_in[15], *eb3=(const float*)d_in[16];
  const float* cW1=(const float*)d_in[17], *cb1=(const float*)d_in[18],
             * cW2=(const float*)d_in[19], *cb2=(const float*)d_in[20],
             * cW3=(const float*)d_in[21], *cb3=(const float*)d_in[22];
  const float* gen_W=(const float*)d_in[23];
  const float* trWq=(const float*)d_in[24], *trbq=(const float*)d_in[25];
  const float* trWk=(const float*)d_in[26], *trbk=(const float*)d_in[27];
  const float* trWv=(const float*)d_in[28], *trbv=(const float*)d_in[29];
  const float* trWe=(const float*)d_in[30];
  const float* trWs=(const float*)d_in[31], *trbs=(const float*)d_in[32];
  const float* linW=(const float*)d_in[33], *linb=(const float*)d_in[34];
  const float* ffW1=(const float*)d_in[35], *ffb1=(const float*)d_in[36];
  const float* ffW2=(const float*)d_in[37], *ffb2=(const float*)d_in[38];
  float* out = (float*)d_out;

  // ---- workspace carve-up (floats) ----
  float* ws = (float*)d_ws;
  size_t off = 0;
  auto alloc = [&](size_t n)->float*{ float* p = ws + off; off += (n + 63) & ~(size_t)63; return p; };
  int*      srcA  = (int*)alloc(EAUG);
  int*      dstA  = (int*)alloc(EAUG);
  int*      cnt   = (int*)alloc(NAUG);
  int*      rowptr= (int*)alloc(NAUG+1);
  int*      cursor= (int*)alloc(NAUG);
  int*      eid   = (int*)alloc(EAUG);
  int*      esrc  = (int*)alloc(EAUG);
  int*      epos  = (int*)alloc(EAUG);
  int*      pdst  = (int*)alloc(EAUG);
  unsigned short* aug_b = (unsigned short*)alloc((size_t)EAUG*DD/2);
  float*    o     = alloc((size_t)NAUG*DD);
  float*    c_emb = alloc((size_t)NG*DD);
  float*    ybuf  = alloc((size_t)NAUG*DD);
  float*    aggsum= alloc((size_t)NAUG*DD);
  float*    xin   = alloc((size_t)NAUG*HC);
  float*    xqkvs = alloc((size_t)NAUG*QS);
  float*    toutb = alloc((size_t)NAUG*HC);
  float*    t1    = alloc((size_t)NAUG*HC);
  float*    wbuf  = alloc((size_t)NAUG*HC);
  float*    ffh   = alloc((size_t)NAUG*256);
  float2*   lgb   = (float2*)alloc((size_t)EAUG*2);
  unsigned short* warena = (unsigned short*)alloc(210432);
  unsigned short* qweb   = (unsigned short*)alloc(3*128*136/2 + 64);
  float*    bqeb  = alloc(3*128);
  if (off*sizeof(float) > ws_size) return;

  const unsigned short* wptr[39];
  int wblk = 0;
  { size_t woff = 0;
    for (int j = 0; j < 39; j++){
      wptr[j] = warena + woff;
      int e = WTAB_H[j][3]*WTAB_H[j][4];
      woff += (size_t)e;
      wblk += cdiv(e, 256);
    } }

  // ---- weight conversion + combined qe weight ----
  WPtrs wp;
  wp.p[0]=trWq; wp.p[1]=trWk; wp.p[2]=trWv; wp.p[3]=trWs; wp.p[4]=gen_W;
  wp.p[5]=linW; wp.p[6]=ffW1; wp.p[7]=ffW2; wp.p[8]=trWe;
  wp.p[9]=xW1; wp.p[10]=xW2; wp.p[11]=xW3;
  wp.p[12]=eW1; wp.p[13]=eW2; wp.p[14]=eW3;
  wp.p[15]=cW1; wp.p[16]=cW2; wp.p[17]=cW3;
  wconv_all_k<<<wblk,256,0,stream>>>(wp, warena);
  qecomb_k<<<dim3(128,3),128,0,stream>>>(trWq, trbq, trWe, qweb, bqeb);

  // ---- setup: edges + CSR ----
  hipMemsetAsync(cnt, 0, sizeof(int)*NAUG, stream);
  hipMemsetAsync(cursor, 0, sizeof(int)*NAUG, stream);
  build_edges_k<<<cdiv(EAUG,256),256,0,stream>>>(edge_index, batch, srcA, dstA, cnt);
  scan_k<<<1,1024,0,stream>>>(cnt, rowptr);
  scatter_k<<<cdiv(EAUG,256),256,0,stream>>>(dstA, rowptr, cursor, eid, epos);
  fill_esrc_k<<<cdiv(EAUG,256),256,0,stream>>>(eid, srcA, esrc);
  fill_pdst_k<<<cdiv(NAUG,16),256,0,stream>>>(rowptr, pdst);

  // ---- input MLPs + pads / loop-attr ----
  mlp3_mfma_k<<<cdiv(NN,64),256,0,stream>>>(x,        NN, 32, wptr[30],wptr[31],wptr[32], xb1,xb2,xb3, nullptr, o,     nullptr);
  mlp3_mfma_k<<<cdiv(NG,64),256,0,stream>>>(cond,     NG, 32, wptr[36],wptr[37],wptr[38], cb1,cb2,cb3, nullptr, c_emb, nullptr);
  mlp3_mfma_k<<<cdiv(NE,64),256,0,stream>>>(edge_attr,NE, 16, wptr[33],wptr[34],wptr[35], eb1,eb2,eb3, epos,    nullptr, aug_b);
  set_ep_k<<<cdiv(2*NN*DD,256),256,0,stream>>>(epos, aug_b);
  loopmean_k<<<cdiv(NAUG,16),256,0,stream>>>(rowptr, epos, aug_b);
  copy_c_o_k<<<cdiv(NG*DD,256),256,0,stream>>>(c_emb, o);
  copy_o_xin_k<<<cdiv(NAUG*DD,256),256,0,stream>>>(o, xin);

  // ---- layers ----
  for (int L=0; L<3; L++){
    const float* lb_i = linb + (size_t)L*DD;
    const float* f1b  = ffb1 + (size_t)L*256;
    const float* f2b  = ffb2 + (size_t)L*DD;
    const unsigned short* genT = wptr[12+L], *linT = wptr[15+L], *ff1T = wptr[18+L], *ff2T = wptr[21+L];
    PW5 pw5;
    pw5.w[0]=wptr[0+L]; pw5.w[1]=wptr[3+L]; pw5.w[2]=wptr[6+L]; pw5.w[3]=wptr[9+L];
    pw5.w[4]=qweb + (size_t)L*128*136;
    pw5.b[0]=trbq+(size_t)L*HC; pw5.b[1]=trbk+(size_t)L*HC;
    pw5.b[2]=trbv+(size_t)L*HC; pw5.b[3]=trbs+(size_t)L*HC;
    pw5.b[4]=bqeb + (size_t)L*128;
    PW2 pwT; pwT.w[0]=wptr[24+2*L]; pwT.w[1]=wptr[25+2*L];

    msg_graph_k<<<4*NG,512,0,stream>>>(o, aug_b, rowptr, esrc, aggsum);
    gemm_mfma( 64, aggsum, o, NAUG, 64, 64, genT, nullptr, 0, nullptr, nullptr, 0, xin+64, HC, stream);
    qkvs5_k<<<dim3(cdiv(NAUG,64),5),256,0,stream>>>(xin, NAUG, pw5, xqkvs);
    scoredot_k<<<cdiv(EAUG,32),512,0,stream>>>(xqkvs, aug_b, pdst, esrc, lgb);
    attn_lite_k<<<4*NG,512,0,stream>>>(xqkvs, lgb, aug_b, rowptr, esrc, t1, wbuf);
    tout2_k<<<dim3(cdiv(NAUG,64),2),256,0,stream>>>(wbuf, NAUG, pwT, t1, xqkvs, toutb);
    gemm_mfma( 64, toutb, nullptr, NAUG, 128, 128, linT, lb_i, 0, o, nullptr, DD, ybuf, DD, stream);
    ln_k<<<NG,256,0,stream>>>(ybuf, o, nullptr);
    gemm_mfma(256, o,   nullptr, NAUG,  64,  64, ff1T, f1b, 1, nullptr, nullptr, 0, ffh, 256, stream);
    gemm_mfma( 64, ffh, nullptr, NAUG, 256, 256, ff2T, f2b, 0, o, nullptr, DD, ybuf, DD, stream);
    ln_k<<<NG,256,0,stream>>>(ybuf, o, xin);
  }

  // ---- outputs ----
  glob_k<<<NG,64,0,stream>>>(o, c_emb, out + (size_t)NN*HC);
  ofinal_k<<<cdiv(NN*HC,256),256,0,stream>>>(o, c_emb, batch, out);
}